// Round 1
// baseline (380.075 us; speedup 1.0000x reference)
//
#include <hip/hip_runtime.h>
#include <hip/hip_bf16.h>

typedef __attribute__((ext_vector_type(4))) float f32x4;
typedef __attribute__((ext_vector_type(8))) short bf16x8;

#define NB 8
#define NS 512
#define NH 16
#define ND 64
#define HID 1024
#define NBH (NB*NH)   // 128
#define NROWS (NB*NS) // 4096

static __device__ __forceinline__ ushort f2bf(float x){
    union{float f; unsigned u;} a; a.f = x;
    unsigned r = a.u + 0x7fffu + ((a.u >> 16) & 1u);
    return (ushort)(r >> 16);
}
static __device__ __forceinline__ float bf2f(ushort x){
    union{unsigned u; float f;} a; a.u = ((unsigned)x) << 16;
    return a.f;
}

// ---------------- kernel 1: sinusoidal rel table (255x64, padded to 256) ---
__global__ void build_tables(ushort* __restrict__ tab, ushort* __restrict__ tabT){
    int t = blockIdx.x * blockDim.x + threadIdx.x;
    if (t >= 256 * 64) return;
    int p = t >> 6, d = t & 63;
    float val = 0.f;
    if (p < 255){
        int i = d >> 1;
        float angle = (float)p / powf(10000.f, (float)i / 32.f);
        val = (d & 1) ? cosf(angle) : sinf(angle);
    }
    ushort b = f2bf(val);
    tab[p * 64 + d]  = b;
    tabT[d * 256 + p] = b;
}

// ---------------- kernel 2: fp32 -> bf16 convert (vectorized x4) ----------
__global__ void cvt_bf16(const float* __restrict__ src, ushort* __restrict__ dst, int n4){
    int i = blockIdx.x * blockDim.x + threadIdx.x;
    if (i >= n4) return;
    float4 v = reinterpret_cast<const float4*>(src)[i];
    ushort4 o;
    o.x = f2bf(v.x); o.y = f2bf(v.y); o.z = f2bf(v.z); o.w = f2bf(v.w);
    reinterpret_cast<ushort4*>(dst)[i] = o;
}

// ---------------- kernel 3: projection GEMM (bf16 MFMA, 128x128 tile) -----
// OUT[m][o] = sum_k X[m][k]*W[o][k] + bias[o]; X:[4096][1024], W:[1024][1024]
// writes bf16, head-split: transpose_out==0 -> [bh][s][d]; ==1 -> [bh][d][s]
__global__ __launch_bounds__(256) void proj_gemm(
    const ushort* __restrict__ X, const ushort* __restrict__ W,
    const float* __restrict__ bias, ushort* __restrict__ out, int transpose_out)
{
    __shared__ ushort lA[128][72];
    __shared__ ushort lB[128][72];
    int m0 = blockIdx.y * 128, n0 = blockIdx.x * 128;
    int tid = threadIdx.x;
    int wave = tid >> 6, lane = tid & 63;
    int wr = (wave >> 1) * 64, wc = (wave & 1) * 64;
    int lrow = lane & 15, lk8 = (lane >> 4) * 8;

    f32x4 acc[4][4] = {};

    for (int k0 = 0; k0 < HID; k0 += 64){
        __syncthreads();
        #pragma unroll
        for (int i = 0; i < 4; ++i){
            int chunk = i * 256 + tid;
            int row = chunk >> 3, col = (chunk & 7) * 8;
            *reinterpret_cast<uint4*>(&lA[row][col]) =
                *reinterpret_cast<const uint4*>(&X[(size_t)(m0 + row) * HID + k0 + col]);
            *reinterpret_cast<uint4*>(&lB[row][col]) =
                *reinterpret_cast<const uint4*>(&W[(size_t)(n0 + row) * HID + k0 + col]);
        }
        __syncthreads();
        #pragma unroll
        for (int ks = 0; ks < 2; ++ks){
            bf16x8 af[4], bfr[4];
            #pragma unroll
            for (int m = 0; m < 4; ++m)
                af[m] = *reinterpret_cast<const bf16x8*>(&lA[wr + m*16 + lrow][ks*32 + lk8]);
            #pragma unroll
            for (int n = 0; n < 4; ++n)
                bfr[n] = *reinterpret_cast<const bf16x8*>(&lB[wc + n*16 + lrow][ks*32 + lk8]);
            #pragma unroll
            for (int m = 0; m < 4; ++m)
                #pragma unroll
                for (int n = 0; n < 4; ++n)
                    acc[m][n] = __builtin_amdgcn_mfma_f32_16x16x32_bf16(af[m], bfr[n], acc[m][n], 0, 0, 0);
        }
    }

    #pragma unroll
    for (int m = 0; m < 4; ++m){
        #pragma unroll
        for (int n = 0; n < 4; ++n){
            int col = n0 + wc + n*16 + lrow;
            float bv = bias[col];
            int h = col >> 6, d = col & 63;
            #pragma unroll
            for (int r = 0; r < 4; ++r){
                int mg = m0 + wr + m*16 + (lane >> 4)*4 + r;
                int b = mg >> 9, s = mg & 511;
                float val = acc[m][n][r] + bv;
                if (!transpose_out)
                    out[(((size_t)(b*NH + h))*NS + s)*ND + d] = f2bf(val);
                else
                    out[(((size_t)(b*NH + h))*ND + d)*NS + s] = f2bf(val);
            }
        }
    }
}

// ---------------- kernel 4: scores = (Q Kext^T)/8 + mask ------------------
// Kext rows: 0..511 = K head rows, 512..767 = rel table rows.
// epilogue: scores[q][k] = (qk + qrel[q][clip(k-q)+127])*0.125 + mask[b][k]
__global__ __launch_bounds__(512) void scores_kernel(
    const ushort* __restrict__ Qb, const ushort* __restrict__ Kb,
    const ushort* __restrict__ tab, const float* __restrict__ mask,
    float* __restrict__ scores)
{
    __shared__ ushort qrel[64][264];
    int bh = blockIdx.y;
    int b  = bh >> 4;
    int q0 = blockIdx.x * 64;
    int wave = threadIdx.x >> 6, lane = threadIdx.x & 63;
    int lrow = lane & 15, lk8 = (lane >> 4) * 8;

    const ushort* Qh = Qb + (size_t)bh * NS * ND;
    const ushort* Kh = Kb + (size_t)bh * NS * ND;

    bf16x8 af[4][2];
    #pragma unroll
    for (int m = 0; m < 4; ++m)
        #pragma unroll
        for (int ks = 0; ks < 2; ++ks)
            af[m][ks] = *reinterpret_cast<const bf16x8*>(&Qh[(size_t)(q0 + m*16 + lrow)*ND + ks*32 + lk8]);

    f32x4 acc[4][6] = {};
    #pragma unroll
    for (int n = 0; n < 6; ++n){
        int c = wave * 96 + n * 16 + lrow;
        const ushort* src = (c < NS) ? &Kh[(size_t)c * ND] : &tab[(size_t)(c - NS) * ND];
        #pragma unroll
        for (int ks = 0; ks < 2; ++ks){
            bf16x8 bfr = *reinterpret_cast<const bf16x8*>(&src[ks*32 + lk8]);
            #pragma unroll
            for (int m = 0; m < 4; ++m)
                acc[m][n] = __builtin_amdgcn_mfma_f32_16x16x32_bf16(af[m][ks], bfr, acc[m][n], 0, 0, 0);
        }
    }

    // stash qrel part (cols >= 512) to LDS
    #pragma unroll
    for (int m = 0; m < 4; ++m){
        #pragma unroll
        for (int n = 0; n < 6; ++n){
            int c = wave * 96 + n * 16 + lrow;
            if (c >= NS){
                int bin = c - NS;
                int rowl = m*16 + (lane >> 4)*4;
                #pragma unroll
                for (int r = 0; r < 4; ++r)
                    qrel[rowl + r][bin] = f2bf(acc[m][n][r]);
            }
        }
    }
    __syncthreads();

    #pragma unroll
    for (int m = 0; m < 4; ++m){
        #pragma unroll
        for (int n = 0; n < 6; ++n){
            int c = wave * 96 + n * 16 + lrow;
            if (c < NS){
                float mk = mask[b * NS + c];
                int rowl = m*16 + (lane >> 4)*4;
                #pragma unroll
                for (int r = 0; r < 4; ++r){
                    int q = q0 + rowl + r;
                    int dd = c - q;
                    dd = min(127, max(-127, dd));
                    float val = (acc[m][n][r] + bf2f(qrel[rowl + r][dd + 127])) * 0.125f + mk;
                    scores[((size_t)bh * NS + q) * NS + c] = val;
                }
            }
        }
    }
}

// ---------------- kernel 5: softmax + PV + P.rel --------------------------
// per block: one (b,h), 32 q-rows. probs -> LDS bf16; pbar bins -> LDS f32.
// ctx[q][d] = sum_k p[q][k] V[k][d] + sum_j pbar[q][j] table[j][d]
__global__ __launch_bounds__(256) void softmax_pv(
    const float* __restrict__ scores, const ushort* __restrict__ vT,
    const ushort* __restrict__ tabT, float* __restrict__ ctx)
{
    __shared__ ushort pL[32][520];
    __shared__ float  pbar[32][264];
    int bh = blockIdx.y;
    int b = bh >> 4, h = bh & 15;
    int q0 = blockIdx.x * 32;
    int wave = threadIdx.x >> 6, lane = threadIdx.x & 63;

    for (int i = threadIdx.x; i < 32 * 264; i += 256)
        (&pbar[0][0])[i] = 0.f;
    __syncthreads();

    const float* srow_base = scores + ((size_t)bh * NS + q0) * NS;
    for (int r = 0; r < 8; ++r){
        int row = wave * 8 + r;
        const float* srow = srow_base + (size_t)row * NS;
        float4 v0 = *reinterpret_cast<const float4*>(srow + lane * 8);
        float4 v1 = *reinterpret_cast<const float4*>(srow + lane * 8 + 4);
        float vals[8] = {v0.x, v0.y, v0.z, v0.w, v1.x, v1.y, v1.z, v1.w};
        float mx = vals[0];
        #pragma unroll
        for (int j = 1; j < 8; ++j) mx = fmaxf(mx, vals[j]);
        #pragma unroll
        for (int off = 32; off >= 1; off >>= 1) mx = fmaxf(mx, __shfl_xor(mx, off));
        float sum = 0.f;
        #pragma unroll
        for (int j = 0; j < 8; ++j){ vals[j] = __expf(vals[j] - mx); sum += vals[j]; }
        #pragma unroll
        for (int off = 32; off >= 1; off >>= 1) sum += __shfl_xor(sum, off);
        float inv = 1.f / sum;
        int qg = q0 + row;
        ushort ob[8];
        #pragma unroll
        for (int j = 0; j < 8; ++j){
            float p = vals[j] * inv;
            ob[j] = f2bf(p);
            int k = lane * 8 + j;
            int dd = min(127, max(-127, k - qg));
            atomicAdd(&pbar[row][dd + 127], p);
        }
        *reinterpret_cast<uint4*>(&pL[row][lane * 8]) = *reinterpret_cast<const uint4*>(ob);
    }
    __syncthreads();

    int lrow = lane & 15, lk8 = (lane >> 4) * 8;
    int d = wave * 16 + lrow;
    const ushort* vTh = vT + ((size_t)bh * ND + d) * NS;
    const ushort* tTd = tabT + (size_t)d * 256;

    f32x4 acc[2] = {};
    for (int k0 = 0; k0 < NS + 256; k0 += 32){
        bf16x8 bfr;
        if (k0 < NS) bfr = *reinterpret_cast<const bf16x8*>(&vTh[k0 + lk8]);
        else         bfr = *reinterpret_cast<const bf16x8*>(&tTd[(k0 - NS) + lk8]);
        #pragma unroll
        for (int m = 0; m < 2; ++m){
            bf16x8 afr;
            if (k0 < NS){
                afr = *reinterpret_cast<const bf16x8*>(&pL[m*16 + lrow][k0 + lk8]);
            } else {
                const float* pr = &pbar[m*16 + lrow][(k0 - NS) + lk8];
                #pragma unroll
                for (int j = 0; j < 8; ++j)
                    reinterpret_cast<ushort*>(&afr)[j] = f2bf(pr[j]);
            }
            acc[m] = __builtin_amdgcn_mfma_f32_16x16x32_bf16(afr, bfr, acc[m], 0, 0, 0);
        }
    }

    #pragma unroll
    for (int m = 0; m < 2; ++m){
        #pragma unroll
        for (int r = 0; r < 4; ++r){
            int q = q0 + m*16 + (lane >> 4)*4 + r;
            ctx[((size_t)b * NS + q) * HID + h * ND + d] = acc[m][r];
        }
    }
}

extern "C" void kernel_launch(void* const* d_in, const int* in_sizes, int n_in,
                              void* d_out, int out_size, void* d_ws, size_t ws_size,
                              hipStream_t stream)
{
    const float* x    = (const float*)d_in[0];
    const float* mask = (const float*)d_in[1];
    const float* Wq   = (const float*)d_in[2];
    const float* bq   = (const float*)d_in[3];
    const float* Wk   = (const float*)d_in[4];
    const float* bk   = (const float*)d_in[5];
    const float* Wv   = (const float*)d_in[6];
    const float* bv   = (const float*)d_in[7];

    float* out = (float*)d_out;
    float* ctx    = out;                      // [8][512][1024]
    float* scores = out + (size_t)NB*NS*HID;  // [8][16][512][512]

    char* ws = (char*)d_ws;
    ushort* x_bf  = (ushort*)ws;                          ws += (size_t)NROWS*HID*2;
    ushort* wq_bf = (ushort*)ws;                          ws += (size_t)HID*HID*2;
    ushort* wk_bf = (ushort*)ws;                          ws += (size_t)HID*HID*2;
    ushort* wv_bf = (ushort*)ws;                          ws += (size_t)HID*HID*2;
    ushort* q_bf  = (ushort*)ws;                          ws += (size_t)NBH*NS*ND*2;
    ushort* k_bf  = (ushort*)ws;                          ws += (size_t)NBH*NS*ND*2;
    ushort* vT_bf = (ushort*)ws;                          ws += (size_t)NBH*NS*ND*2;
    ushort* tab   = (ushort*)ws;                          ws += 256*64*2;
    ushort* tabT  = (ushort*)ws;                          ws += 64*256*2;

    build_tables<<<64, 256, 0, stream>>>(tab, tabT);

    cvt_bf16<<<(NROWS*HID/4 + 255)/256, 256, 0, stream>>>(x,  x_bf,  NROWS*HID/4);
    cvt_bf16<<<(HID*HID/4 + 255)/256,  256, 0, stream>>>(Wq, wq_bf, HID*HID/4);
    cvt_bf16<<<(HID*HID/4 + 255)/256,  256, 0, stream>>>(Wk, wk_bf, HID*HID/4);
    cvt_bf16<<<(HID*HID/4 + 255)/256,  256, 0, stream>>>(Wv, wv_bf, HID*HID/4);

    dim3 pg(HID/128, NROWS/128);
    proj_gemm<<<pg, 256, 0, stream>>>(x_bf, wq_bf, bq, q_bf, 0);
    proj_gemm<<<pg, 256, 0, stream>>>(x_bf, wk_bf, bk, k_bf, 0);
    proj_gemm<<<pg, 256, 0, stream>>>(x_bf, wv_bf, bv, vT_bf, 1);

    scores_kernel<<<dim3(NS/64, NBH), 512, 0, stream>>>(q_bf, k_bf, tab, mask, scores);

    softmax_pv<<<dim3(NS/32, NBH), 256, 0, stream>>>(scores, vT_bf, tabT, ctx);
}

// Round 3
// 280.923 us; speedup vs baseline: 1.3530x; 1.3530x over previous
//
#include <hip/hip_runtime.h>
#include <hip/hip_bf16.h>

typedef __attribute__((ext_vector_type(4))) float f32x4;
typedef __attribute__((ext_vector_type(8))) short bf16x8;

#define NB 8
#define NS 512
#define NH 16
#define ND 64
#define HID 1024
#define NBH (NB*NH)   // 128
#define NROWS (NB*NS) // 4096

static __device__ __forceinline__ ushort f2bf(float x){
    union{float f; unsigned u;} a; a.f = x;
    unsigned r = a.u + 0x7fffu + ((a.u >> 16) & 1u);
    return (ushort)(r >> 16);
}
static __device__ __forceinline__ float bf2f(ushort x){
    union{unsigned u; float f;} a; a.u = ((unsigned)x) << 16;
    return a.f;
}

// ---------------- kernel 1: sinusoidal rel table (255x64, padded to 256) ---
__global__ void build_tables(ushort* __restrict__ tab, ushort* __restrict__ tabT){
    int t = blockIdx.x * blockDim.x + threadIdx.x;
    if (t >= 256 * 64) return;
    int p = t >> 6, d = t & 63;
    float val = 0.f;
    if (p < 255){
        int i = d >> 1;
        float angle = (float)p / powf(10000.f, (float)i / 32.f);
        val = (d & 1) ? cosf(angle) : sinf(angle);
    }
    ushort b = f2bf(val);
    tab[p * 64 + d]  = b;
    tabT[d * 256 + p] = b;
}

// ---------------- kernel 2: fp32 -> bf16 convert (vectorized x4) ----------
__global__ void cvt_bf16(const float* __restrict__ src, ushort* __restrict__ dst, int n4){
    int i = blockIdx.x * blockDim.x + threadIdx.x;
    if (i >= n4) return;
    float4 v = reinterpret_cast<const float4*>(src)[i];
    ushort4 o;
    o.x = f2bf(v.x); o.y = f2bf(v.y); o.z = f2bf(v.z); o.w = f2bf(v.w);
    reinterpret_cast<ushort4*>(dst)[i] = o;
}

// ---------------- kernel 3: merged QKV projection GEMM --------------------
__global__ __launch_bounds__(256) void proj_gemm_qkv(
    const ushort* __restrict__ X,
    const ushort* __restrict__ Wqp, const ushort* __restrict__ Wkp, const ushort* __restrict__ Wvp,
    const float* __restrict__ bqp, const float* __restrict__ bkp, const float* __restrict__ bvp,
    ushort* __restrict__ outQ, ushort* __restrict__ outK, ushort* __restrict__ outV)
{
    __shared__ ushort lA[128][72];
    __shared__ ushort lB[128][72];
    int sel = blockIdx.x >> 3;
    const ushort* W   = sel == 0 ? Wqp : (sel == 1 ? Wkp : Wvp);
    const float* bias = sel == 0 ? bqp : (sel == 1 ? bkp : bvp);
    ushort* out       = sel == 0 ? outQ : (sel == 1 ? outK : outV);
    int n0 = (blockIdx.x & 7) * 128;
    int m0 = blockIdx.y * 128;
    int tid = threadIdx.x;
    int wave = tid >> 6, lane = tid & 63;
    int wr = (wave >> 1) * 64, wc = (wave & 1) * 64;
    int lrow = lane & 15, lk8 = (lane >> 4) * 8;

    f32x4 acc[4][4] = {};

    for (int k0 = 0; k0 < HID; k0 += 64){
        __syncthreads();
        #pragma unroll
        for (int i = 0; i < 4; ++i){
            int chunk = i * 256 + tid;
            int row = chunk >> 3, col = (chunk & 7) * 8;
            *reinterpret_cast<uint4*>(&lA[row][col]) =
                *reinterpret_cast<const uint4*>(&X[(size_t)(m0 + row) * HID + k0 + col]);
            *reinterpret_cast<uint4*>(&lB[row][col]) =
                *reinterpret_cast<const uint4*>(&W[(size_t)(n0 + row) * HID + k0 + col]);
        }
        __syncthreads();
        #pragma unroll
        for (int ks = 0; ks < 2; ++ks){
            bf16x8 af[4], bfr[4];
            #pragma unroll
            for (int m = 0; m < 4; ++m)
                af[m] = *reinterpret_cast<const bf16x8*>(&lA[wr + m*16 + lrow][ks*32 + lk8]);
            #pragma unroll
            for (int n = 0; n < 4; ++n)
                bfr[n] = *reinterpret_cast<const bf16x8*>(&lB[wc + n*16 + lrow][ks*32 + lk8]);
            #pragma unroll
            for (int m = 0; m < 4; ++m)
                #pragma unroll
                for (int n = 0; n < 4; ++n)
                    acc[m][n] = __builtin_amdgcn_mfma_f32_16x16x32_bf16(af[m], bfr[n], acc[m][n], 0, 0, 0);
        }
    }

    #pragma unroll
    for (int m = 0; m < 4; ++m){
        #pragma unroll
        for (int n = 0; n < 4; ++n){
            int col = n0 + wc + n*16 + lrow;
            float bv = bias[col];
            int h = col >> 6, d = col & 63;
            #pragma unroll
            for (int r = 0; r < 4; ++r){
                int mg = m0 + wr + m*16 + (lane >> 4)*4 + r;
                int b = mg >> 9, s = mg & 511;
                float val = acc[m][n][r] + bv;
                if (sel != 2)
                    out[(((size_t)(b*NH + h))*NS + s)*ND + d] = f2bf(val);
                else
                    out[(((size_t)(b*NH + h))*ND + d)*NS + s] = f2bf(val);
            }
        }
    }
}

// ---------------- kernel 4: fused scores+softmax+PV+P.rel -----------------
// Block: one (b,h), 32 q rows, 4 waves x 192 ext-cols (512 K + 256 rel bins).
// SEPARATE qrel / pbar arrays (no LDS reuse) + full zero-init of pL/pbar:
// every LDS slot ever read is deterministically written first.
__global__ __launch_bounds__(256) void fused_attn(
    const ushort* __restrict__ Qb, const ushort* __restrict__ Kb,
    const ushort* __restrict__ vT, const ushort* __restrict__ tab,
    const ushort* __restrict__ tabT, const float* __restrict__ mask,
    float* __restrict__ scores, float* __restrict__ ctx)
{
    __shared__ ushort pL[32][520];     // normalized probs (bf16), cols 0..511 + pad
    __shared__ ushort qrel[32][256];   // q x rel-bin scores (phase B/C only)
    __shared__ ushort pbar[32][264];   // binned probs (phase E/F/G only)
    __shared__ float  rmax[32][4];
    __shared__ float  rsum[32][4];
    __shared__ float  rleft[32][4];
    __shared__ float  rright[32][4];

    const int bh = blockIdx.y;
    const int b = bh >> 4, h = bh & 15;
    const int q0 = blockIdx.x * 32;
    const int wave = threadIdx.x >> 6, lane = threadIdx.x & 63;
    const int lrow = lane & 15, g = lane >> 4, lk8 = g * 8;

    // ---- phase 0: deterministic LDS init (pL pad + pbar fully) ----
    for (int i = threadIdx.x; i < 32 * 520; i += 256) (&pL[0][0])[i] = 0;
    for (int i = threadIdx.x; i < 32 * 264; i += 256) (&pbar[0][0])[i] = 0;
    __syncthreads();

    const ushort* Qh = Qb + (size_t)bh * NS * ND;
    const ushort* Kh = Kb + (size_t)bh * NS * ND;

    // ---- phase A: extended QK^T (cols 0..511 = K rows, 512..767 = table) ----
    bf16x8 af[2][2];
    #pragma unroll
    for (int m = 0; m < 2; ++m)
        #pragma unroll
        for (int ks = 0; ks < 2; ++ks)
            af[m][ks] = *reinterpret_cast<const bf16x8*>(&Qh[(size_t)(q0 + m*16 + lrow)*ND + ks*32 + lk8]);

    f32x4 acc[2][12];
    #pragma unroll
    for (int m = 0; m < 2; ++m)
        #pragma unroll
        for (int n = 0; n < 12; ++n)
            acc[m][n] = (f32x4){0.f, 0.f, 0.f, 0.f};

    #pragma unroll
    for (int n = 0; n < 12; ++n){
        int cbase = wave*192 + n*16;  // uniform per (wave,n)
        const ushort* src = (cbase < NS) ? &Kh[(size_t)(cbase + lrow)*ND]
                                         : &tab[(size_t)(cbase - NS + lrow)*ND];
        #pragma unroll
        for (int ks = 0; ks < 2; ++ks){
            bf16x8 bfr = *reinterpret_cast<const bf16x8*>(&src[ks*32 + lk8]);
            #pragma unroll
            for (int m = 0; m < 2; ++m)
                acc[m][n] = __builtin_amdgcn_mfma_f32_16x16x32_bf16(af[m][ks], bfr, acc[m][n], 0, 0, 0);
        }
    }

    // ---- phase B: stash qrel (cols >= 512) ----
    #pragma unroll
    for (int n = 0; n < 12; ++n){
        int cbase = wave*192 + n*16;
        if (cbase >= NS){
            int bin = cbase - NS + lrow;
            #pragma unroll
            for (int m = 0; m < 2; ++m){
                int rowl = m*16 + g*4;
                #pragma unroll
                for (int r = 0; r < 4; ++r)
                    qrel[rowl + r][bin] = f2bf(acc[m][n][r]);
            }
        }
    }
    __syncthreads();

    // ---- phase C: final scores = (qk + qrel_gather)/8 + mask; write HBM ----
    #pragma unroll
    for (int n = 0; n < 12; ++n){
        int cbase = wave*192 + n*16;
        if (cbase < NS){
            int c = cbase + lrow;
            float mk = mask[b*NS + c];
            #pragma unroll
            for (int m = 0; m < 2; ++m){
                #pragma unroll
                for (int r = 0; r < 4; ++r){
                    int row = m*16 + g*4 + r;
                    int q = q0 + row;
                    int dd = min(127, max(-127, c - q));
                    float val = (acc[m][n][r] + bf2f(qrel[row][dd + 127])) * 0.125f + mk;
                    acc[m][n][r] = val;
                    scores[((size_t)bh*NS + q)*NS + c] = val;
                }
            }
        }
    }

    // ---- phase D1: row max ----
    float mx[2][4];
    #pragma unroll
    for (int m = 0; m < 2; ++m)
        #pragma unroll
        for (int r = 0; r < 4; ++r) mx[m][r] = -1e30f;
    #pragma unroll
    for (int n = 0; n < 12; ++n){
        int cbase = wave*192 + n*16;
        if (cbase < NS)
            #pragma unroll
            for (int m = 0; m < 2; ++m)
                #pragma unroll
                for (int r = 0; r < 4; ++r) mx[m][r] = fmaxf(mx[m][r], acc[m][n][r]);
    }
    #pragma unroll
    for (int off = 1; off < 16; off <<= 1)
        #pragma unroll
        for (int m = 0; m < 2; ++m)
            #pragma unroll
            for (int r = 0; r < 4; ++r) mx[m][r] = fmaxf(mx[m][r], __shfl_xor(mx[m][r], off));
    if (lrow == 0)
        #pragma unroll
        for (int m = 0; m < 2; ++m)
            #pragma unroll
            for (int r = 0; r < 4; ++r) rmax[m*16 + g*4 + r][wave] = mx[m][r];
    __syncthreads();
    float M[2][4];
    #pragma unroll
    for (int m = 0; m < 2; ++m)
        #pragma unroll
        for (int r = 0; r < 4; ++r){
            int row = m*16 + g*4 + r;
            M[m][r] = fmaxf(fmaxf(rmax[row][0], rmax[row][1]), fmaxf(rmax[row][2], rmax[row][3]));
        }

    // ---- phase D2: exp + total/prefix/suffix sums ----
    float st[2][4] = {}, sl[2][4] = {}, sr[2][4] = {};
    #pragma unroll
    for (int n = 0; n < 12; ++n){
        int cbase = wave*192 + n*16;
        if (cbase < NS){
            int c = cbase + lrow;
            #pragma unroll
            for (int m = 0; m < 2; ++m){
                #pragma unroll
                for (int r = 0; r < 4; ++r){
                    int q = q0 + m*16 + g*4 + r;
                    float e = __expf(acc[m][n][r] - M[m][r]);
                    acc[m][n][r] = e;
                    st[m][r] += e;
                    if (c <= q - 127) sl[m][r] += e;
                    if (c >= q + 127) sr[m][r] += e;
                }
            }
        }
    }
    #pragma unroll
    for (int off = 1; off < 16; off <<= 1)
        #pragma unroll
        for (int m = 0; m < 2; ++m)
            #pragma unroll
            for (int r = 0; r < 4; ++r){
                st[m][r] += __shfl_xor(st[m][r], off);
                sl[m][r] += __shfl_xor(sl[m][r], off);
                sr[m][r] += __shfl_xor(sr[m][r], off);
            }
    if (lrow == 0)
        #pragma unroll
        for (int m = 0; m < 2; ++m)
            #pragma unroll
            for (int r = 0; r < 4; ++r){
                int row = m*16 + g*4 + r;
                rsum[row][wave] = st[m][r];
                rleft[row][wave] = sl[m][r];
                rright[row][wave] = sr[m][r];
            }
    __syncthreads();
    float inv[2][4], Lv[2][4], Rv[2][4];
    #pragma unroll
    for (int m = 0; m < 2; ++m)
        #pragma unroll
        for (int r = 0; r < 4; ++r){
            int row = m*16 + g*4 + r;
            float T = rsum[row][0] + rsum[row][1] + rsum[row][2] + rsum[row][3];
            float iv = 1.f / T;
            inv[m][r] = iv;
            Lv[m][r] = (rleft[row][0] + rleft[row][1] + rleft[row][2] + rleft[row][3]) * iv;
            Rv[m][r] = (rright[row][0] + rright[row][1] + rright[row][2] + rright[row][3]) * iv;
        }

    // ---- phase E: normalized probs -> pL; edge bins -> pbar ----
    #pragma unroll
    for (int n = 0; n < 12; ++n){
        int cbase = wave*192 + n*16;
        if (cbase < NS){
            int c = cbase + lrow;
            #pragma unroll
            for (int m = 0; m < 2; ++m)
                #pragma unroll
                for (int r = 0; r < 4; ++r)
                    pL[m*16 + g*4 + r][c] = f2bf(acc[m][n][r] * inv[m][r]);
        }
    }
    if (wave == 0 && lrow == 0){
        #pragma unroll
        for (int m = 0; m < 2; ++m)
            #pragma unroll
            for (int r = 0; r < 4; ++r){
                int row = m*16 + g*4 + r;
                pbar[row][0]   = f2bf(Lv[m][r]);
                pbar[row][254] = f2bf(Rv[m][r]);
            }
    }
    __syncthreads();

    // ---- phase F: middle pbar bins = shifted copy of p row ----
    for (int idx = threadIdx.x; idx < 32*256; idx += 256){
        int row = idx >> 8, j = idx & 255;
        if (j == 0 || j >= 254) continue;
        int col = q0 + row + j - 127;
        pbar[row][j] = (col >= 0 && col < NS) ? pL[row][col] : (ushort)0;
    }
    __syncthreads();

    // ---- phase G: ctx = P·V + pbar·table (extended K MFMA) ----
    const int d = wave*16 + lrow;
    const ushort* vTh = vT + ((size_t)bh*ND + d)*NS;
    const ushort* tTd = tabT + (size_t)d*256;
    f32x4 o[2];
    o[0] = (f32x4){0.f,0.f,0.f,0.f};
    o[1] = (f32x4){0.f,0.f,0.f,0.f};
    for (int k0 = 0; k0 < NS; k0 += 32){
        bf16x8 bv_ = *reinterpret_cast<const bf16x8*>(&vTh[k0 + lk8]);
        #pragma unroll
        for (int m = 0; m < 2; ++m){
            bf16x8 pa = *reinterpret_cast<const bf16x8*>(&pL[m*16 + lrow][k0 + lk8]);
            o[m] = __builtin_amdgcn_mfma_f32_16x16x32_bf16(pa, bv_, o[m], 0, 0, 0);
        }
    }
    #pragma unroll
    for (int k0 = 0; k0 < 256; k0 += 32){
        bf16x8 bv_ = *reinterpret_cast<const bf16x8*>(&tTd[k0 + lk8]);
        #pragma unroll
        for (int m = 0; m < 2; ++m){
            bf16x8 pa = *reinterpret_cast<const bf16x8*>(&pbar[m*16 + lrow][k0 + lk8]);
            o[m] = __builtin_amdgcn_mfma_f32_16x16x32_bf16(pa, bv_, o[m], 0, 0, 0);
        }
    }
    #pragma unroll
    for (int m = 0; m < 2; ++m)
        #pragma unroll
        for (int r = 0; r < 4; ++r){
            int q = q0 + m*16 + g*4 + r;
            ctx[((size_t)b*NS + q)*HID + h*ND + d] = o[m][r];
        }
}

extern "C" void kernel_launch(void* const* d_in, const int* in_sizes, int n_in,
                              void* d_out, int out_size, void* d_ws, size_t ws_size,
                              hipStream_t stream)
{
    const float* x    = (const float*)d_in[0];
    const float* mask = (const float*)d_in[1];
    const float* Wq   = (const float*)d_in[2];
    const float* bq   = (const float*)d_in[3];
    const float* Wk   = (const float*)d_in[4];
    const float* bk   = (const float*)d_in[5];
    const float* Wv   = (const float*)d_in[6];
    const float* bv   = (const float*)d_in[7];

    float* out = (float*)d_out;
    float* ctx    = out;                      // [8][512][1024]
    float* scores = out + (size_t)NB*NS*HID;  // [8][16][512][512]

    char* ws = (char*)d_ws;
    ushort* x_bf  = (ushort*)ws;  ws += (size_t)NROWS*HID*2;
    ushort* wq_bf = (ushort*)ws;  ws += (size_t)HID*HID*2;
    ushort* wk_bf = (ushort*)ws;  ws += (size_t)HID*HID*2;
    ushort* wv_bf = (ushort*)ws;  ws += (size_t)HID*HID*2;
    ushort* q_bf  = (ushort*)ws;  ws += (size_t)NBH*NS*ND*2;
    ushort* k_bf  = (ushort*)ws;  ws += (size_t)NBH*NS*ND*2;
    ushort* vT_bf = (ushort*)ws;  ws += (size_t)NBH*NS*ND*2;
    ushort* tab   = (ushort*)ws;  ws += 256*64*2;
    ushort* tabT  = (ushort*)ws;  ws += 64*256*2;

    build_tables<<<64, 256, 0, stream>>>(tab, tabT);

    cvt_bf16<<<(NROWS*HID/4 + 255)/256, 256, 0, stream>>>(x,  x_bf,  NROWS*HID/4);
    cvt_bf16<<<(HID*HID/4 + 255)/256,  256, 0, stream>>>(Wq, wq_bf, HID*HID/4);
    cvt_bf16<<<(HID*HID/4 + 255)/256,  256, 0, stream>>>(Wk, wk_bf, HID*HID/4);
    cvt_bf16<<<(HID*HID/4 + 255)/256,  256, 0, stream>>>(Wv, wv_bf, HID*HID/4);

    proj_gemm_qkv<<<dim3(24, 32), 256, 0, stream>>>(
        x_bf, wq_bf, wk_bf, wv_bf, bq, bk, bv, q_bf, k_bf, vT_bf);

    fused_attn<<<dim3(NS/32, NBH), 256, 0, stream>>>(
        q_bf, k_bf, vT_bf, tab, tabT, mask, scores, ctx);
}

// Round 4
// 200.052 us; speedup vs baseline: 1.8999x; 1.4043x over previous
//
#include <hip/hip_runtime.h>
#include <hip/hip_bf16.h>

typedef __attribute__((ext_vector_type(4))) float f32x4;
typedef __attribute__((ext_vector_type(8))) short bf16x8;

#define NB 8
#define NS 512
#define NH 16
#define ND 64
#define HID 1024
#define NBH (NB*NH)   // 128
#define NROWS (NB*NS) // 4096

static __device__ __forceinline__ ushort f2bf(float x){
    union{float f; unsigned u;} a; a.f = x;
    unsigned r = a.u + 0x7fffu + ((a.u >> 16) & 1u);
    return (ushort)(r >> 16);
}
static __device__ __forceinline__ float bf2f(ushort x){
    union{unsigned u; float f;} a; a.u = ((unsigned)x) << 16;
    return a.f;
}

// ---------------- kernel 1: sinusoidal rel table (255x64, padded to 256) ---
__global__ void build_tables(ushort* __restrict__ tab, ushort* __restrict__ tabT){
    int t = blockIdx.x * blockDim.x + threadIdx.x;
    if (t >= 256 * 64) return;
    int p = t >> 6, d = t & 63;
    float val = 0.f;
    if (p < 255){
        int i = d >> 1;
        float angle = (float)p / powf(10000.f, (float)i / 32.f);
        val = (d & 1) ? cosf(angle) : sinf(angle);
    }
    ushort b = f2bf(val);
    tab[p * 64 + d]  = b;
    tabT[d * 256 + p] = b;
}

// ---------------- kernel 2: fp32 -> bf16 convert (vectorized x4) ----------
__global__ void cvt_bf16(const float* __restrict__ src, ushort* __restrict__ dst, int n4){
    int i = blockIdx.x * blockDim.x + threadIdx.x;
    if (i >= n4) return;
    float4 v = reinterpret_cast<const float4*>(src)[i];
    ushort4 o;
    o.x = f2bf(v.x); o.y = f2bf(v.y); o.z = f2bf(v.z); o.w = f2bf(v.w);
    reinterpret_cast<ushort4*>(dst)[i] = o;
}

// ---------------- kernel 3: merged QKV projection GEMM --------------------
__global__ __launch_bounds__(256) void proj_gemm_qkv(
    const ushort* __restrict__ X,
    const ushort* __restrict__ Wqp, const ushort* __restrict__ Wkp, const ushort* __restrict__ Wvp,
    const float* __restrict__ bqp, const float* __restrict__ bkp, const float* __restrict__ bvp,
    ushort* __restrict__ outQ, ushort* __restrict__ outK, ushort* __restrict__ outV)
{
    __shared__ ushort lA[128][72];
    __shared__ ushort lB[128][72];
    int sel = blockIdx.x >> 3;
    const ushort* W   = sel == 0 ? Wqp : (sel == 1 ? Wkp : Wvp);
    const float* bias = sel == 0 ? bqp : (sel == 1 ? bkp : bvp);
    ushort* out       = sel == 0 ? outQ : (sel == 1 ? outK : outV);
    int n0 = (blockIdx.x & 7) * 128;
    int m0 = blockIdx.y * 128;
    int tid = threadIdx.x;
    int wave = tid >> 6, lane = tid & 63;
    int wr = (wave >> 1) * 64, wc = (wave & 1) * 64;
    int lrow = lane & 15, lk8 = (lane >> 4) * 8;

    f32x4 acc[4][4] = {};

    for (int k0 = 0; k0 < HID; k0 += 64){
        __syncthreads();
        #pragma unroll
        for (int i = 0; i < 4; ++i){
            int chunk = i * 256 + tid;
            int row = chunk >> 3, col = (chunk & 7) * 8;
            *reinterpret_cast<uint4*>(&lA[row][col]) =
                *reinterpret_cast<const uint4*>(&X[(size_t)(m0 + row) * HID + k0 + col]);
            *reinterpret_cast<uint4*>(&lB[row][col]) =
                *reinterpret_cast<const uint4*>(&W[(size_t)(n0 + row) * HID + k0 + col]);
        }
        __syncthreads();
        #pragma unroll
        for (int ks = 0; ks < 2; ++ks){
            bf16x8 af[4], bfr[4];
            #pragma unroll
            for (int m = 0; m < 4; ++m)
                af[m] = *reinterpret_cast<const bf16x8*>(&lA[wr + m*16 + lrow][ks*32 + lk8]);
            #pragma unroll
            for (int n = 0; n < 4; ++n)
                bfr[n] = *reinterpret_cast<const bf16x8*>(&lB[wc + n*16 + lrow][ks*32 + lk8]);
            #pragma unroll
            for (int m = 0; m < 4; ++m)
                #pragma unroll
                for (int n = 0; n < 4; ++n)
                    acc[m][n] = __builtin_amdgcn_mfma_f32_16x16x32_bf16(af[m], bfr[n], acc[m][n], 0, 0, 0);
        }
    }

    #pragma unroll
    for (int m = 0; m < 4; ++m){
        #pragma unroll
        for (int n = 0; n < 4; ++n){
            int col = n0 + wc + n*16 + lrow;
            float bv = bias[col];
            int h = col >> 6, d = col & 63;
            #pragma unroll
            for (int r = 0; r < 4; ++r){
                int mg = m0 + wr + m*16 + (lane >> 4)*4 + r;
                int b = mg >> 9, s = mg & 511;
                float val = acc[m][n][r] + bv;
                if (sel != 2)
                    out[(((size_t)(b*NH + h))*NS + s)*ND + d] = f2bf(val);
                else
                    out[(((size_t)(b*NH + h))*ND + d)*NS + s] = f2bf(val);
            }
        }
    }
}

// ---------------- kernel 4: fused scores+softmax+PV+P.rel -----------------
// Block: one (b,h), 16 q rows, 4 waves. Balanced: each wave owns 8 K-tiles
// (128 cols) + 4 table-tiles (64 bins). ~35 KB LDS -> 4 blocks/CU.
// pbar trick: bins 1..253 shifted copies of p; bins 0/254 prefix/suffix sums.
__global__ __launch_bounds__(256) void fused_attn(
    const ushort* __restrict__ Qb, const ushort* __restrict__ Kb,
    const ushort* __restrict__ vT, const ushort* __restrict__ tab,
    const ushort* __restrict__ tabT, const float* __restrict__ mask,
    float* __restrict__ scores, float* __restrict__ ctx)
{
    __shared__ ushort pL[16][520];     // normalized probs (bf16), cols 0..511 + pad
    __shared__ ushort qrel[16][264];   // q x rel-bin scores (padded stride: 528B)
    __shared__ ushort pbar[16][264];   // binned probs
    __shared__ float  rmax[16][4];
    __shared__ float  rsum[16][4];
    __shared__ float  rleft[16][4];
    __shared__ float  rright[16][4];

    const int bh = blockIdx.y;
    const int b = bh >> 4, h = bh & 15;
    const int q0 = blockIdx.x * 16;
    const int wave = threadIdx.x >> 6, lane = threadIdx.x & 63;
    const int lrow = lane & 15, g = lane >> 4, lk8 = g * 8;

    // ---- phase 0: deterministic LDS init ----
    for (int i = threadIdx.x; i < 16 * 520; i += 256) (&pL[0][0])[i] = 0;
    for (int i = threadIdx.x; i < 16 * 264; i += 256) (&pbar[0][0])[i] = 0;
    for (int i = threadIdx.x; i < 16 * 264; i += 256) (&qrel[0][0])[i] = 0;
    __syncthreads();

    const ushort* Qh = Qb + (size_t)bh * NS * ND;
    const ushort* Kh = Kb + (size_t)bh * NS * ND;

    // ---- phase A: extended QK^T ----
    // tiles n=0..7: K cols cbase = wave*128 + n*16
    // tiles n=8..11: table bins binbase = wave*64 + (n-8)*16
    bf16x8 af[2];
    #pragma unroll
    for (int ks = 0; ks < 2; ++ks)
        af[ks] = *reinterpret_cast<const bf16x8*>(&Qh[(size_t)(q0 + lrow)*ND + ks*32 + lk8]);

    f32x4 acc[12];
    #pragma unroll
    for (int n = 0; n < 12; ++n) acc[n] = (f32x4){0.f, 0.f, 0.f, 0.f};

    #pragma unroll
    for (int n = 0; n < 12; ++n){
        const ushort* src = (n < 8) ? &Kh[(size_t)(wave*128 + n*16 + lrow)*ND]
                                    : &tab[(size_t)(wave*64 + (n-8)*16 + lrow)*ND];
        #pragma unroll
        for (int ks = 0; ks < 2; ++ks){
            bf16x8 bfr = *reinterpret_cast<const bf16x8*>(&src[ks*32 + lk8]);
            acc[n] = __builtin_amdgcn_mfma_f32_16x16x32_bf16(af[ks], bfr, acc[n], 0, 0, 0);
        }
    }

    // ---- phase B: stash qrel (table tiles) ----
    #pragma unroll
    for (int n = 8; n < 12; ++n){
        int bin = wave*64 + (n-8)*16 + lrow;
        int rowl = g*4;
        #pragma unroll
        for (int r = 0; r < 4; ++r)
            qrel[rowl + r][bin] = f2bf(acc[n][r]);
    }
    __syncthreads();

    // ---- phase C: scores = (qk + qrel_gather)/8 + mask; write HBM ----
    #pragma unroll
    for (int n = 0; n < 8; ++n){
        int c = wave*128 + n*16 + lrow;
        float mk = mask[b*NS + c];
        #pragma unroll
        for (int r = 0; r < 4; ++r){
            int row = g*4 + r;
            int q = q0 + row;
            int dd = min(127, max(-127, c - q));
            float val = (acc[n][r] + bf2f(qrel[row][dd + 127])) * 0.125f + mk;
            acc[n][r] = val;
            scores[((size_t)bh*NS + q)*NS + c] = val;
        }
    }

    // ---- phase D1: row max ----
    float mx[4];
    #pragma unroll
    for (int r = 0; r < 4; ++r) mx[r] = -1e30f;
    #pragma unroll
    for (int n = 0; n < 8; ++n)
        #pragma unroll
        for (int r = 0; r < 4; ++r) mx[r] = fmaxf(mx[r], acc[n][r]);
    #pragma unroll
    for (int off = 1; off < 16; off <<= 1)
        #pragma unroll
        for (int r = 0; r < 4; ++r) mx[r] = fmaxf(mx[r], __shfl_xor(mx[r], off));
    if (lrow == 0)
        #pragma unroll
        for (int r = 0; r < 4; ++r) rmax[g*4 + r][wave] = mx[r];
    __syncthreads();
    float M[4];
    #pragma unroll
    for (int r = 0; r < 4; ++r){
        int row = g*4 + r;
        M[r] = fmaxf(fmaxf(rmax[row][0], rmax[row][1]), fmaxf(rmax[row][2], rmax[row][3]));
    }

    // ---- phase D2: exp + total/prefix/suffix sums ----
    float st[4] = {}, sl[4] = {}, sr[4] = {};
    #pragma unroll
    for (int n = 0; n < 8; ++n){
        int c = wave*128 + n*16 + lrow;
        #pragma unroll
        for (int r = 0; r < 4; ++r){
            int q = q0 + g*4 + r;
            float e = __expf(acc[n][r] - M[r]);
            acc[n][r] = e;
            st[r] += e;
            if (c <= q - 127) sl[r] += e;
            if (c >= q + 127) sr[r] += e;
        }
    }
    #pragma unroll
    for (int off = 1; off < 16; off <<= 1)
        #pragma unroll
        for (int r = 0; r < 4; ++r){
            st[r] += __shfl_xor(st[r], off);
            sl[r] += __shfl_xor(sl[r], off);
            sr[r] += __shfl_xor(sr[r], off);
        }
    if (lrow == 0)
        #pragma unroll
        for (int r = 0; r < 4; ++r){
            int row = g*4 + r;
            rsum[row][wave] = st[r];
            rleft[row][wave] = sl[r];
            rright[row][wave] = sr[r];
        }
    __syncthreads();
    float inv[4], Lv[4], Rv[4];
    #pragma unroll
    for (int r = 0; r < 4; ++r){
        int row = g*4 + r;
        float T = rsum[row][0] + rsum[row][1] + rsum[row][2] + rsum[row][3];
        float iv = 1.f / T;
        inv[r] = iv;
        Lv[r] = (rleft[row][0] + rleft[row][1] + rleft[row][2] + rleft[row][3]) * iv;
        Rv[r] = (rright[row][0] + rright[row][1] + rright[row][2] + rright[row][3]) * iv;
    }

    // ---- phase E: normalized probs -> pL; edge bins -> pbar ----
    #pragma unroll
    for (int n = 0; n < 8; ++n){
        int c = wave*128 + n*16 + lrow;
        #pragma unroll
        for (int r = 0; r < 4; ++r)
            pL[g*4 + r][c] = f2bf(acc[n][r] * inv[r]);
    }
    if (wave == 0 && lrow == 0){
        #pragma unroll
        for (int r = 0; r < 4; ++r){
            int row = g*4 + r;
            pbar[row][0]   = f2bf(Lv[r]);
            pbar[row][254] = f2bf(Rv[r]);
        }
    }
    __syncthreads();

    // ---- phase F: middle pbar bins = shifted copy of p row ----
    for (int idx = threadIdx.x; idx < 16*256; idx += 256){
        int row = idx >> 8, j = idx & 255;
        if (j == 0 || j >= 254) continue;
        int col = q0 + row + j - 127;
        pbar[row][j] = (col >= 0 && col < NS) ? pL[row][col] : (ushort)0;
    }
    __syncthreads();

    // ---- phase G: ctx = P·V + pbar·table (two acc chains) ----
    const int d = wave*16 + lrow;
    const ushort* vTh = vT + ((size_t)bh*ND + d)*NS;
    const ushort* tTd = tabT + (size_t)d*256;
    f32x4 o0 = (f32x4){0.f,0.f,0.f,0.f};
    f32x4 o1 = (f32x4){0.f,0.f,0.f,0.f};
    #pragma unroll
    for (int k0 = 0; k0 < NS; k0 += 64){
        bf16x8 bv0 = *reinterpret_cast<const bf16x8*>(&vTh[k0 + lk8]);
        bf16x8 pa0 = *reinterpret_cast<const bf16x8*>(&pL[lrow][k0 + lk8]);
        o0 = __builtin_amdgcn_mfma_f32_16x16x32_bf16(pa0, bv0, o0, 0, 0, 0);
        bf16x8 bv1 = *reinterpret_cast<const bf16x8*>(&vTh[k0 + 32 + lk8]);
        bf16x8 pa1 = *reinterpret_cast<const bf16x8*>(&pL[lrow][k0 + 32 + lk8]);
        o1 = __builtin_amdgcn_mfma_f32_16x16x32_bf16(pa1, bv1, o1, 0, 0, 0);
    }
    #pragma unroll
    for (int k0 = 0; k0 < 256; k0 += 64){
        bf16x8 bv0 = *reinterpret_cast<const bf16x8*>(&tTd[k0 + lk8]);
        bf16x8 pa0 = *reinterpret_cast<const bf16x8*>(&pbar[lrow][k0 + lk8]);
        o0 = __builtin_amdgcn_mfma_f32_16x16x32_bf16(pa0, bv0, o0, 0, 0, 0);
        bf16x8 bv1 = *reinterpret_cast<const bf16x8*>(&tTd[k0 + 32 + lk8]);
        bf16x8 pa1 = *reinterpret_cast<const bf16x8*>(&pbar[lrow][k0 + 32 + lk8]);
        o1 = __builtin_amdgcn_mfma_f32_16x16x32_bf16(pa1, bv1, o1, 0, 0, 0);
    }
    #pragma unroll
    for (int r = 0; r < 4; ++r){
        int q = q0 + g*4 + r;
        ctx[((size_t)b*NS + q)*HID + h*ND + d] = o0[r] + o1[r];
    }
}

extern "C" void kernel_launch(void* const* d_in, const int* in_sizes, int n_in,
                              void* d_out, int out_size, void* d_ws, size_t ws_size,
                              hipStream_t stream)
{
    const float* x    = (const float*)d_in[0];
    const float* mask = (const float*)d_in[1];
    const float* Wq   = (const float*)d_in[2];
    const float* bq   = (const float*)d_in[3];
    const float* Wk   = (const float*)d_in[4];
    const float* bk   = (const float*)d_in[5];
    const float* Wv   = (const float*)d_in[6];
    const float* bv   = (const float*)d_in[7];

    float* out = (float*)d_out;
    float* ctx    = out;                      // [8][512][1024]
    float* scores = out + (size_t)NB*NS*HID;  // [8][16][512][512]

    char* ws = (char*)d_ws;
    ushort* x_bf  = (ushort*)ws;  ws += (size_t)NROWS*HID*2;
    ushort* wq_bf = (ushort*)ws;  ws += (size_t)HID*HID*2;
    ushort* wk_bf = (ushort*)ws;  ws += (size_t)HID*HID*2;
    ushort* wv_bf = (ushort*)ws;  ws += (size_t)HID*HID*2;
    ushort* q_bf  = (ushort*)ws;  ws += (size_t)NBH*NS*ND*2;
    ushort* k_bf  = (ushort*)ws;  ws += (size_t)NBH*NS*ND*2;
    ushort* vT_bf = (ushort*)ws;  ws += (size_t)NBH*NS*ND*2;
    ushort* tab   = (ushort*)ws;  ws += 256*64*2;
    ushort* tabT  = (ushort*)ws;  ws += 64*256*2;

    build_tables<<<64, 256, 0, stream>>>(tab, tabT);

    cvt_bf16<<<(NROWS*HID/4 + 255)/256, 256, 0, stream>>>(x,  x_bf,  NROWS*HID/4);
    cvt_bf16<<<(HID*HID/4 + 255)/256,  256, 0, stream>>>(Wq, wq_bf, HID*HID/4);
    cvt_bf16<<<(HID*HID/4 + 255)/256,  256, 0, stream>>>(Wk, wk_bf, HID*HID/4);
    cvt_bf16<<<(HID*HID/4 + 255)/256,  256, 0, stream>>>(Wv, wv_bf, HID*HID/4);

    proj_gemm_qkv<<<dim3(24, 32), 256, 0, stream>>>(
        x_bf, wq_bf, wk_bf, wv_bf, bq, bk, bv, q_bf, k_bf, vT_bf);

    fused_attn<<<dim3(NS/16, NBH), 256, 0, stream>>>(
        q_bf, k_bf, vT_bf, tab, tabT, mask, scores, ctx);
}

// Round 5
// 192.645 us; speedup vs baseline: 1.9729x; 1.0385x over previous
//
#include <hip/hip_runtime.h>
#include <hip/hip_bf16.h>

typedef __attribute__((ext_vector_type(4))) float f32x4;
typedef __attribute__((ext_vector_type(8))) short bf16x8;

#define NB 8
#define NS 512
#define NH 16
#define ND 64
#define HID 1024
#define NBH (NB*NH)   // 128
#define NROWS (NB*NS) // 4096

static __device__ __forceinline__ ushort f2bf(float x){
    union{float f; unsigned u;} a; a.f = x;
    unsigned r = a.u + 0x7fffu + ((a.u >> 16) & 1u);
    return (ushort)(r >> 16);
}
static __device__ __forceinline__ float bf2f(ushort x){
    union{unsigned u; float f;} a; a.u = ((unsigned)x) << 16;
    return a.f;
}

// ---------------- kernel 1: sinusoidal rel table (255x64, padded to 256) ---
// row 255 and tabT col 255 are EXACT ZERO (relied on by fused_attn's aliased
// pbar buffer: stale bin 255 multiplies tabT col 255 == 0).
__global__ void build_tables(ushort* __restrict__ tab, ushort* __restrict__ tabT){
    int t = blockIdx.x * blockDim.x + threadIdx.x;
    if (t >= 256 * 64) return;
    int p = t >> 6, d = t & 63;
    float val = 0.f;
    if (p < 255){
        int i = d >> 1;
        float angle = (float)p / powf(10000.f, (float)i / 32.f);
        val = (d & 1) ? cosf(angle) : sinf(angle);
    }
    ushort b = f2bf(val);
    tab[p * 64 + d]  = b;
    tabT[d * 256 + p] = b;
}

// ---------------- kernel 2a: fp32 -> bf16 convert (hidden states) ----------
__global__ void cvt_bf16(const float* __restrict__ src, ushort* __restrict__ dst, int n4){
    int i = blockIdx.x * blockDim.x + threadIdx.x;
    if (i >= n4) return;
    float4 v = reinterpret_cast<const float4*>(src)[i];
    ushort4 o;
    o.x = f2bf(v.x); o.y = f2bf(v.y); o.z = f2bf(v.z); o.w = f2bf(v.w);
    reinterpret_cast<ushort4*>(dst)[i] = o;
}

// ---------------- kernel 2b: fp32 -> bf16 convert, 3 weights in one launch -
__global__ void cvt_bf16_w3(const float* __restrict__ w0, const float* __restrict__ w1,
                            const float* __restrict__ w2, ushort* __restrict__ o0,
                            ushort* __restrict__ o1, ushort* __restrict__ o2, int n4){
    int i = blockIdx.x * blockDim.x + threadIdx.x;
    if (i >= n4) return;
    const float* src = blockIdx.y == 0 ? w0 : (blockIdx.y == 1 ? w1 : w2);
    ushort* dst      = blockIdx.y == 0 ? o0 : (blockIdx.y == 1 ? o1 : o2);
    float4 v = reinterpret_cast<const float4*>(src)[i];
    ushort4 o;
    o.x = f2bf(v.x); o.y = f2bf(v.y); o.z = f2bf(v.z); o.w = f2bf(v.w);
    reinterpret_cast<ushort4*>(dst)[i] = o;
}

// ---------------- kernel 3: merged QKV projection GEMM --------------------
__global__ __launch_bounds__(256) void proj_gemm_qkv(
    const ushort* __restrict__ X,
    const ushort* __restrict__ Wqp, const ushort* __restrict__ Wkp, const ushort* __restrict__ Wvp,
    const float* __restrict__ bqp, const float* __restrict__ bkp, const float* __restrict__ bvp,
    ushort* __restrict__ outQ, ushort* __restrict__ outK, ushort* __restrict__ outV)
{
    __shared__ ushort lA[128][72];
    __shared__ ushort lB[128][72];
    int sel = blockIdx.x >> 3;
    const ushort* W   = sel == 0 ? Wqp : (sel == 1 ? Wkp : Wvp);
    const float* bias = sel == 0 ? bqp : (sel == 1 ? bkp : bvp);
    ushort* out       = sel == 0 ? outQ : (sel == 1 ? outK : outV);
    int n0 = (blockIdx.x & 7) * 128;
    int m0 = blockIdx.y * 128;
    int tid = threadIdx.x;
    int wave = tid >> 6, lane = tid & 63;
    int wr = (wave >> 1) * 64, wc = (wave & 1) * 64;
    int lrow = lane & 15, lk8 = (lane >> 4) * 8;

    f32x4 acc[4][4] = {};

    for (int k0 = 0; k0 < HID; k0 += 64){
        __syncthreads();
        #pragma unroll
        for (int i = 0; i < 4; ++i){
            int chunk = i * 256 + tid;
            int row = chunk >> 3, col = (chunk & 7) * 8;
            *reinterpret_cast<uint4*>(&lA[row][col]) =
                *reinterpret_cast<const uint4*>(&X[(size_t)(m0 + row) * HID + k0 + col]);
            *reinterpret_cast<uint4*>(&lB[row][col]) =
                *reinterpret_cast<const uint4*>(&W[(size_t)(n0 + row) * HID + k0 + col]);
        }
        __syncthreads();
        #pragma unroll
        for (int ks = 0; ks < 2; ++ks){
            bf16x8 af[4], bfr[4];
            #pragma unroll
            for (int m = 0; m < 4; ++m)
                af[m] = *reinterpret_cast<const bf16x8*>(&lA[wr + m*16 + lrow][ks*32 + lk8]);
            #pragma unroll
            for (int n = 0; n < 4; ++n)
                bfr[n] = *reinterpret_cast<const bf16x8*>(&lB[wc + n*16 + lrow][ks*32 + lk8]);
            #pragma unroll
            for (int m = 0; m < 4; ++m)
                #pragma unroll
                for (int n = 0; n < 4; ++n)
                    acc[m][n] = __builtin_amdgcn_mfma_f32_16x16x32_bf16(af[m], bfr[n], acc[m][n], 0, 0, 0);
        }
    }

    #pragma unroll
    for (int m = 0; m < 4; ++m){
        #pragma unroll
        for (int n = 0; n < 4; ++n){
            int col = n0 + wc + n*16 + lrow;
            float bv = bias[col];
            int h = col >> 6, d = col & 63;
            #pragma unroll
            for (int r = 0; r < 4; ++r){
                int mg = m0 + wr + m*16 + (lane >> 4)*4 + r;
                int b = mg >> 9, s = mg & 511;
                float val = acc[m][n][r] + bv;
                if (sel != 2)
                    out[(((size_t)(b*NH + h))*NS + s)*ND + d] = f2bf(val);
                else
                    out[(((size_t)(b*NH + h))*ND + d)*NS + s] = f2bf(val);
            }
        }
    }
}

// ---------------- kernel 4: fused scores+softmax+PV+P.rel -----------------
// Block: one (b,h), 16 q rows, 4 waves; each wave owns 8 K-tiles + 4 table-
// tiles. qq[] is qrel in phases B/C, pbar in phases E/F/G (live ranges
// separated by the D1 barrier). ~26 KB LDS -> 6 blocks/CU.
// Determinism: every LDS slot read is written earlier in the same launch;
// the only stale slot (qq[r][255], old qrel) multiplies tabT col 255 == 0.
__global__ __launch_bounds__(256) void fused_attn(
    const ushort* __restrict__ Qb, const ushort* __restrict__ Kb,
    const ushort* __restrict__ vT, const ushort* __restrict__ tab,
    const ushort* __restrict__ tabT, const float* __restrict__ mask,
    float* __restrict__ scores, float* __restrict__ ctx)
{
    __shared__ ushort pL[16][520];     // normalized probs (bf16)
    __shared__ ushort qq[16][264];     // qrel (B/C) then pbar (E/F/G)
    __shared__ float  rmax[16][4];
    __shared__ float  rsum[16][4];
    __shared__ float  rleft[16][4];
    __shared__ float  rright[16][4];

    const int bh = blockIdx.y;
    const int b = bh >> 4, h = bh & 15;
    const int q0 = blockIdx.x * 16;
    const int wave = threadIdx.x >> 6, lane = threadIdx.x & 63;
    const int lrow = lane & 15, g = lane >> 4, lk8 = g * 8;

    const ushort* Qh = Qb + (size_t)bh * NS * ND;
    const ushort* Kh = Kb + (size_t)bh * NS * ND;

    // ---- phase A: extended QK^T ----
    bf16x8 af[2];
    #pragma unroll
    for (int ks = 0; ks < 2; ++ks)
        af[ks] = *reinterpret_cast<const bf16x8*>(&Qh[(size_t)(q0 + lrow)*ND + ks*32 + lk8]);

    f32x4 acc[12];
    #pragma unroll
    for (int n = 0; n < 12; ++n) acc[n] = (f32x4){0.f, 0.f, 0.f, 0.f};

    #pragma unroll
    for (int n = 0; n < 12; ++n){
        const ushort* src = (n < 8) ? &Kh[(size_t)(wave*128 + n*16 + lrow)*ND]
                                    : &tab[(size_t)(wave*64 + (n-8)*16 + lrow)*ND];
        #pragma unroll
        for (int ks = 0; ks < 2; ++ks){
            bf16x8 bfr = *reinterpret_cast<const bf16x8*>(&src[ks*32 + lk8]);
            acc[n] = __builtin_amdgcn_mfma_f32_16x16x32_bf16(af[ks], bfr, acc[n], 0, 0, 0);
        }
    }

    // ---- phase B: stash qrel (table tiles) into qq ----
    #pragma unroll
    for (int n = 8; n < 12; ++n){
        int bin = wave*64 + (n-8)*16 + lrow;
        int rowl = g*4;
        #pragma unroll
        for (int r = 0; r < 4; ++r)
            qq[rowl + r][bin] = f2bf(acc[n][r]);
    }
    __syncthreads();

    // ---- phase C: scores = (qk + qrel_gather)/8 + mask; write HBM ----
    #pragma unroll
    for (int n = 0; n < 8; ++n){
        int c = wave*128 + n*16 + lrow;
        float mk = mask[b*NS + c];
        #pragma unroll
        for (int r = 0; r < 4; ++r){
            int row = g*4 + r;
            int q = q0 + row;
            int dd = min(127, max(-127, c - q));
            float val = (acc[n][r] + bf2f(qq[row][dd + 127])) * 0.125f + mk;
            acc[n][r] = val;
            scores[((size_t)bh*NS + q)*NS + c] = val;
        }
    }

    // ---- phase D1: row max ----
    float mx[4];
    #pragma unroll
    for (int r = 0; r < 4; ++r) mx[r] = -1e30f;
    #pragma unroll
    for (int n = 0; n < 8; ++n)
        #pragma unroll
        for (int r = 0; r < 4; ++r) mx[r] = fmaxf(mx[r], acc[n][r]);
    #pragma unroll
    for (int off = 1; off < 16; off <<= 1)
        #pragma unroll
        for (int r = 0; r < 4; ++r) mx[r] = fmaxf(mx[r], __shfl_xor(mx[r], off));
    if (lrow == 0)
        #pragma unroll
        for (int r = 0; r < 4; ++r) rmax[g*4 + r][wave] = mx[r];
    __syncthreads();   // after this barrier no wave reads qq-as-qrel again
    float M[4];
    #pragma unroll
    for (int r = 0; r < 4; ++r){
        int row = g*4 + r;
        M[r] = fmaxf(fmaxf(rmax[row][0], rmax[row][1]), fmaxf(rmax[row][2], rmax[row][3]));
    }

    // ---- phase D2: exp + total/prefix/suffix sums ----
    float st[4] = {}, sl[4] = {}, sr[4] = {};
    #pragma unroll
    for (int n = 0; n < 8; ++n){
        int c = wave*128 + n*16 + lrow;
        #pragma unroll
        for (int r = 0; r < 4; ++r){
            int q = q0 + g*4 + r;
            float e = __expf(acc[n][r] - M[r]);
            acc[n][r] = e;
            st[r] += e;
            if (c <= q - 127) sl[r] += e;
            if (c >= q + 127) sr[r] += e;
        }
    }
    #pragma unroll
    for (int off = 1; off < 16; off <<= 1)
        #pragma unroll
        for (int r = 0; r < 4; ++r){
            st[r] += __shfl_xor(st[r], off);
            sl[r] += __shfl_xor(sl[r], off);
            sr[r] += __shfl_xor(sr[r], off);
        }
    if (lrow == 0)
        #pragma unroll
        for (int r = 0; r < 4; ++r){
            int row = g*4 + r;
            rsum[row][wave] = st[r];
            rleft[row][wave] = sl[r];
            rright[row][wave] = sr[r];
        }
    __syncthreads();
    float inv[4], Lv[4], Rv[4];
    #pragma unroll
    for (int r = 0; r < 4; ++r){
        int row = g*4 + r;
        float T = rsum[row][0] + rsum[row][1] + rsum[row][2] + rsum[row][3];
        float iv = 1.f / T;
        inv[r] = iv;
        Lv[r] = (rleft[row][0] + rleft[row][1] + rleft[row][2] + rleft[row][3]) * iv;
        Rv[r] = (rright[row][0] + rright[row][1] + rright[row][2] + rright[row][3]) * iv;
    }

    // ---- phase E: normalized probs -> pL; edge bins -> qq(pbar) ----
    #pragma unroll
    for (int n = 0; n < 8; ++n){
        int c = wave*128 + n*16 + lrow;
        #pragma unroll
        for (int r = 0; r < 4; ++r)
            pL[g*4 + r][c] = f2bf(acc[n][r] * inv[r]);
    }
    if (wave == 0 && lrow == 0){
        #pragma unroll
        for (int r = 0; r < 4; ++r){
            int row = g*4 + r;
            qq[row][0]   = f2bf(Lv[r]);
            qq[row][254] = f2bf(Rv[r]);
        }
    }
    __syncthreads();

    // ---- phase F: middle pbar bins = shifted copy of p row ----
    for (int idx = threadIdx.x; idx < 16*256; idx += 256){
        int row = idx >> 8, j = idx & 255;
        if (j == 0 || j >= 254) continue;
        int col = q0 + row + j - 127;
        qq[row][j] = (col >= 0 && col < NS) ? pL[row][col] : (ushort)0;
    }
    __syncthreads();

    // ---- phase G: ctx = P·V + pbar·table (two acc chains) ----
    const int d = wave*16 + lrow;
    const ushort* vTh = vT + ((size_t)bh*ND + d)*NS;
    const ushort* tTd = tabT + (size_t)d*256;
    f32x4 o0 = (f32x4){0.f,0.f,0.f,0.f};
    f32x4 o1 = (f32x4){0.f,0.f,0.f,0.f};
    #pragma unroll
    for (int k0 = 0; k0 < NS; k0 += 64){
        bf16x8 bv0 = *reinterpret_cast<const bf16x8*>(&vTh[k0 + lk8]);
        bf16x8 pa0 = *reinterpret_cast<const bf16x8*>(&pL[lrow][k0 + lk8]);
        o0 = __builtin_amdgcn_mfma_f32_16x16x32_bf16(pa0, bv0, o0, 0, 0, 0);
        bf16x8 bv1 = *reinterpret_cast<const bf16x8*>(&vTh[k0 + 32 + lk8]);
        bf16x8 pa1 = *reinterpret_cast<const bf16x8*>(&pL[lrow][k0 + 32 + lk8]);
        o1 = __builtin_amdgcn_mfma_f32_16x16x32_bf16(pa1, bv1, o1, 0, 0, 0);
    }
    #pragma unroll
    for (int k0 = 0; k0 < 256; k0 += 64){
        bf16x8 bv0 = *reinterpret_cast<const bf16x8*>(&tTd[k0 + lk8]);
        bf16x8 pa0 = *reinterpret_cast<const bf16x8*>(&qq[lrow][k0 + lk8]);
        o0 = __builtin_amdgcn_mfma_f32_16x16x32_bf16(pa0, bv0, o0, 0, 0, 0);
        bf16x8 bv1 = *reinterpret_cast<const bf16x8*>(&tTd[k0 + 32 + lk8]);
        bf16x8 pa1 = *reinterpret_cast<const bf16x8*>(&qq[lrow][k0 + 32 + lk8]);
        o1 = __builtin_amdgcn_mfma_f32_16x16x32_bf16(pa1, bv1, o1, 0, 0, 0);
    }
    #pragma unroll
    for (int r = 0; r < 4; ++r){
        int q = q0 + g*4 + r;
        ctx[((size_t)b*NS + q)*HID + h*ND + d] = o0[r] + o1[r];
    }
}

extern "C" void kernel_launch(void* const* d_in, const int* in_sizes, int n_in,
                              void* d_out, int out_size, void* d_ws, size_t ws_size,
                              hipStream_t stream)
{
    const float* x    = (const float*)d_in[0];
    const float* mask = (const float*)d_in[1];
    const float* Wq   = (const float*)d_in[2];
    const float* bq   = (const float*)d_in[3];
    const float* Wk   = (const float*)d_in[4];
    const float* bk   = (const float*)d_in[5];
    const float* Wv   = (const float*)d_in[6];
    const float* bv   = (const float*)d_in[7];

    float* out = (float*)d_out;
    float* ctx    = out;                      // [8][512][1024]
    float* scores = out + (size_t)NB*NS*HID;  // [8][16][512][512]

    char* ws = (char*)d_ws;
    ushort* x_bf  = (ushort*)ws;  ws += (size_t)NROWS*HID*2;
    ushort* wq_bf = (ushort*)ws;  ws += (size_t)HID*HID*2;
    ushort* wk_bf = (ushort*)ws;  ws += (size_t)HID*HID*2;
    ushort* wv_bf = (ushort*)ws;  ws += (size_t)HID*HID*2;
    ushort* q_bf  = (ushort*)ws;  ws += (size_t)NBH*NS*ND*2;
    ushort* k_bf  = (ushort*)ws;  ws += (size_t)NBH*NS*ND*2;
    ushort* vT_bf = (ushort*)ws;  ws += (size_t)NBH*NS*ND*2;
    ushort* tab   = (ushort*)ws;  ws += 256*64*2;
    ushort* tabT  = (ushort*)ws;  ws += 64*256*2;

    build_tables<<<64, 256, 0, stream>>>(tab, tabT);

    cvt_bf16<<<(NROWS*HID/4 + 255)/256, 256, 0, stream>>>(x, x_bf, NROWS*HID/4);
    cvt_bf16_w3<<<dim3((HID*HID/4 + 255)/256, 3), 256, 0, stream>>>(
        Wq, Wk, Wv, wq_bf, wk_bf, wv_bf, HID*HID/4);

    proj_gemm_qkv<<<dim3(24, 32), 256, 0, stream>>>(
        x_bf, wq_bf, wk_bf, wv_bf, bq, bk, bv, q_bf, k_bf, vT_bf);

    fused_attn<<<dim3(NS/16, NBH), 256, 0, stream>>>(
        q_bf, k_bf, vT_bf, tab, tabT, mask, scores, ctx);
}

// Round 6
// 182.418 us; speedup vs baseline: 2.0835x; 1.0561x over previous
//
#include <hip/hip_runtime.h>
#include <hip/hip_bf16.h>

typedef __attribute__((ext_vector_type(4))) float f32x4;
typedef __attribute__((ext_vector_type(8))) short bf16x8;

#define NB 8
#define NS 512
#define NH 16
#define ND 64
#define HID 1024
#define NBH (NB*NH)   // 128
#define NROWS (NB*NS) // 4096

static __device__ __forceinline__ ushort f2bf(float x){
    union{float f; unsigned u;} a; a.f = x;
    unsigned r = a.u + 0x7fffu + ((a.u >> 16) & 1u);
    return (ushort)(r >> 16);
}
static __device__ __forceinline__ float bf2f(ushort x){
    union{unsigned u; float f;} a; a.u = ((unsigned)x) << 16;
    return a.f;
}

// ---------------- kernel 1: sinusoidal rel table (255x64, padded to 256) ---
// row 255 and tabT col 255 are EXACT ZERO (relied on by fused_attn's aliased
// pbar buffer: stale bin 255 multiplies tabT col 255 == 0).
__global__ void build_tables(ushort* __restrict__ tab, ushort* __restrict__ tabT){
    int t = blockIdx.x * blockDim.x + threadIdx.x;
    if (t >= 256 * 64) return;
    int p = t >> 6, d = t & 63;
    float val = 0.f;
    if (p < 255){
        int i = d >> 1;
        float angle = (float)p / powf(10000.f, (float)i / 32.f);
        val = (d & 1) ? cosf(angle) : sinf(angle);
    }
    ushort b = f2bf(val);
    tab[p * 64 + d]  = b;
    tabT[d * 256 + p] = b;
}

// ---------------- kernel 2a: fp32 -> bf16 convert (hidden states) ----------
__global__ void cvt_bf16(const float* __restrict__ src, ushort* __restrict__ dst, int n4){
    int i = blockIdx.x * blockDim.x + threadIdx.x;
    if (i >= n4) return;
    float4 v = reinterpret_cast<const float4*>(src)[i];
    ushort4 o;
    o.x = f2bf(v.x); o.y = f2bf(v.y); o.z = f2bf(v.z); o.w = f2bf(v.w);
    reinterpret_cast<ushort4*>(dst)[i] = o;
}

// ---------------- kernel 2b: fp32 -> bf16 convert, 3 weights in one launch -
__global__ void cvt_bf16_w3(const float* __restrict__ w0, const float* __restrict__ w1,
                            const float* __restrict__ w2, ushort* __restrict__ o0,
                            ushort* __restrict__ o1, ushort* __restrict__ o2, int n4){
    int i = blockIdx.x * blockDim.x + threadIdx.x;
    if (i >= n4) return;
    const float* src = blockIdx.y == 0 ? w0 : (blockIdx.y == 1 ? w1 : w2);
    ushort* dst      = blockIdx.y == 0 ? o0 : (blockIdx.y == 1 ? o1 : o2);
    float4 v = reinterpret_cast<const float4*>(src)[i];
    ushort4 o;
    o.x = f2bf(v.x); o.y = f2bf(v.y); o.z = f2bf(v.z); o.w = f2bf(v.w);
    reinterpret_cast<ushort4*>(dst)[i] = o;
}

// ---------------- kernel 3: merged QKV projection GEMM --------------------
__global__ __launch_bounds__(256) void proj_gemm_qkv(
    const ushort* __restrict__ X,
    const ushort* __restrict__ Wqp, const ushort* __restrict__ Wkp, const ushort* __restrict__ Wvp,
    const float* __restrict__ bqp, const float* __restrict__ bkp, const float* __restrict__ bvp,
    ushort* __restrict__ outQ, ushort* __restrict__ outK, ushort* __restrict__ outV)
{
    __shared__ ushort lA[128][72];
    __shared__ ushort lB[128][72];
    int sel = blockIdx.x >> 3;
    const ushort* W   = sel == 0 ? Wqp : (sel == 1 ? Wkp : Wvp);
    const float* bias = sel == 0 ? bqp : (sel == 1 ? bkp : bvp);
    ushort* out       = sel == 0 ? outQ : (sel == 1 ? outK : outV);
    int n0 = (blockIdx.x & 7) * 128;
    int m0 = blockIdx.y * 128;
    int tid = threadIdx.x;
    int wave = tid >> 6, lane = tid & 63;
    int wr = (wave >> 1) * 64, wc = (wave & 1) * 64;
    int lrow = lane & 15, lk8 = (lane >> 4) * 8;

    f32x4 acc[4][4] = {};

    for (int k0 = 0; k0 < HID; k0 += 64){
        __syncthreads();
        #pragma unroll
        for (int i = 0; i < 4; ++i){
            int chunk = i * 256 + tid;
            int row = chunk >> 3, col = (chunk & 7) * 8;
            *reinterpret_cast<uint4*>(&lA[row][col]) =
                *reinterpret_cast<const uint4*>(&X[(size_t)(m0 + row) * HID + k0 + col]);
            *reinterpret_cast<uint4*>(&lB[row][col]) =
                *reinterpret_cast<const uint4*>(&W[(size_t)(n0 + row) * HID + k0 + col]);
        }
        __syncthreads();
        #pragma unroll
        for (int ks = 0; ks < 2; ++ks){
            bf16x8 af[4], bfr[4];
            #pragma unroll
            for (int m = 0; m < 4; ++m)
                af[m] = *reinterpret_cast<const bf16x8*>(&lA[wr + m*16 + lrow][ks*32 + lk8]);
            #pragma unroll
            for (int n = 0; n < 4; ++n)
                bfr[n] = *reinterpret_cast<const bf16x8*>(&lB[wc + n*16 + lrow][ks*32 + lk8]);
            #pragma unroll
            for (int m = 0; m < 4; ++m)
                #pragma unroll
                for (int n = 0; n < 4; ++n)
                    acc[m][n] = __builtin_amdgcn_mfma_f32_16x16x32_bf16(af[m], bfr[n], acc[m][n], 0, 0, 0);
        }
    }

    #pragma unroll
    for (int m = 0; m < 4; ++m){
        #pragma unroll
        for (int n = 0; n < 4; ++n){
            int col = n0 + wc + n*16 + lrow;
            float bv = bias[col];
            int h = col >> 6, d = col & 63;
            #pragma unroll
            for (int r = 0; r < 4; ++r){
                int mg = m0 + wr + m*16 + (lane >> 4)*4 + r;
                int b = mg >> 9, s = mg & 511;
                float val = acc[m][n][r] + bv;
                if (sel != 2)
                    out[(((size_t)(b*NH + h))*NS + s)*ND + d] = f2bf(val);
                else
                    out[(((size_t)(b*NH + h))*ND + d)*NS + s] = f2bf(val);
            }
        }
    }
}

// ---------------- kernel 4: fused scores+softmax+PV+P.rel -----------------
// Block: one (b,h), 16 q rows, 4 waves. SWAPPED QK^T: mfma(Kext, Q) gives
// C[row=k][col=q] -> each lane owns ONE q row with 4 consecutive k per reg:
// float4 score stores, ushort4 LDS writes, in-lane softmax sums + 2 shuffles.
// NO max subtraction: |scores| <~ 12 analytically, exp() safe in f32,
// softmax is shift-invariant.
// qq[] is qrel in B/C, pbar in E/F/G (live ranges split by the C->E barrier).
// Determinism: qq fully written in B each launch; pL cols 0..511 written in E
// before any read; pL pads and stale qq[*][255] (x tabT col 255 == 0) are the
// only never-refreshed slots and are never read / multiply zero.
__global__ __launch_bounds__(256) void fused_attn(
    const ushort* __restrict__ Qb, const ushort* __restrict__ Kb,
    const ushort* __restrict__ vT, const ushort* __restrict__ tab,
    const ushort* __restrict__ tabT, const float* __restrict__ mask,
    float* __restrict__ scores, float* __restrict__ ctx)
{
    __shared__ ushort pL[16][520];     // normalized probs (bf16)
    __shared__ ushort qq[16][264];     // qrel (B/C) then pbar (E/F/G)
    __shared__ float  rsum[16][4];
    __shared__ float  rleft[16][4];
    __shared__ float  rright[16][4];

    const int bh = blockIdx.x;         // bh fastest -> all q-blocks of one bh
    const int b = bh >> 4, h = bh & 15;//   land on the same XCD (bh % 8)
    const int q0 = blockIdx.y * 16;
    const int wave = threadIdx.x >> 6, lane = threadIdx.x & 63;
    const int lrow = lane & 15, g = lane >> 4, lk8 = g * 8;

    const ushort* Qh = Qb + (size_t)bh * NS * ND;
    const ushort* Kh = Kb + (size_t)bh * NS * ND;

    // ---- phase A: extended QK^T, swapped operands ----
    // B-operand = Q rows (col of output = q), A-operand = Kext rows (row = k).
    bf16x8 qf[2];
    #pragma unroll
    for (int ks = 0; ks < 2; ++ks)
        qf[ks] = *reinterpret_cast<const bf16x8*>(&Qh[(size_t)(q0 + lrow)*ND + ks*32 + lk8]);

    f32x4 acc[12];
    #pragma unroll
    for (int n = 0; n < 12; ++n) acc[n] = (f32x4){0.f, 0.f, 0.f, 0.f};

    #pragma unroll
    for (int n = 0; n < 12; ++n){
        const ushort* src = (n < 8) ? &Kh[(size_t)(wave*128 + n*16 + lrow)*ND]
                                    : &tab[(size_t)(wave*64 + (n-8)*16 + lrow)*ND];
        #pragma unroll
        for (int ks = 0; ks < 2; ++ks){
            bf16x8 kf = *reinterpret_cast<const bf16x8*>(&src[ks*32 + lk8]);
            acc[n] = __builtin_amdgcn_mfma_f32_16x16x32_bf16(kf, qf[ks], acc[n], 0, 0, 0);
        }
    }

    // ---- phase B: stash qrel: lane owns q=lrow, bins consecutive in r ----
    #pragma unroll
    for (int n = 8; n < 12; ++n){
        ushort4 w;
        w.x = f2bf(acc[n][0]); w.y = f2bf(acc[n][1]);
        w.z = f2bf(acc[n][2]); w.w = f2bf(acc[n][3]);
        *reinterpret_cast<ushort4*>(&qq[lrow][wave*64 + (n-8)*16 + g*4]) = w;
    }
    __syncthreads();

    // ---- phase C: scores + mask -> HBM (float4) ; exp ; partial sums ----
    const int q = q0 + lrow;
    float st = 0.f, sl = 0.f, sr = 0.f;
    #pragma unroll
    for (int n = 0; n < 8; ++n){
        int kbase = wave*128 + n*16 + g*4;
        float4 mk4 = *reinterpret_cast<const float4*>(&mask[b*NS + kbase]);
        float mk[4] = {mk4.x, mk4.y, mk4.z, mk4.w};
        float sv[4];
        #pragma unroll
        for (int r = 0; r < 4; ++r){
            int k = kbase + r;
            int dd = min(127, max(-127, k - q));
            float val = (acc[n][r] + bf2f(qq[lrow][dd + 127])) * 0.125f + mk[r];
            sv[r] = val;
            float e = __expf(val);
            acc[n][r] = e;
            st += e;
            if (k <= q - 127) sl += e;
            if (k >= q + 127) sr += e;
        }
        *reinterpret_cast<float4*>(&scores[((size_t)bh*NS + q)*NS + kbase]) =
            *reinterpret_cast<const float4*>(sv);
    }
    // combine the 4 g-groups (same q, different k slices)
    st += __shfl_xor(st, 16); st += __shfl_xor(st, 32);
    sl += __shfl_xor(sl, 16); sl += __shfl_xor(sl, 32);
    sr += __shfl_xor(sr, 16); sr += __shfl_xor(sr, 32);
    if (lane < 16){
        rsum[lrow][wave] = st;
        rleft[lrow][wave] = sl;
        rright[lrow][wave] = sr;
    }
    __syncthreads();   // also ends qq-as-qrel liveness

    float T  = rsum[lrow][0] + rsum[lrow][1] + rsum[lrow][2] + rsum[lrow][3];
    float iv = 1.f / T;
    float Lv = (rleft[lrow][0] + rleft[lrow][1] + rleft[lrow][2] + rleft[lrow][3]) * iv;
    float Rv = (rright[lrow][0] + rright[lrow][1] + rright[lrow][2] + rright[lrow][3]) * iv;

    // ---- phase E: normalized probs -> pL (ushort4); edge bins -> qq ----
    #pragma unroll
    for (int n = 0; n < 8; ++n){
        int kbase = wave*128 + n*16 + g*4;
        ushort4 w;
        w.x = f2bf(acc[n][0] * iv); w.y = f2bf(acc[n][1] * iv);
        w.z = f2bf(acc[n][2] * iv); w.w = f2bf(acc[n][3] * iv);
        *reinterpret_cast<ushort4*>(&pL[lrow][kbase]) = w;
    }
    if (wave == 0 && lane < 16){
        qq[lrow][0]   = f2bf(Lv);
        qq[lrow][254] = f2bf(Rv);
    }
    __syncthreads();

    // ---- phase F: middle pbar bins = shifted copy of p row ----
    for (int idx = threadIdx.x; idx < 16*256; idx += 256){
        int row = idx >> 8, j = idx & 255;
        if (j == 0 || j >= 254) continue;
        int col = q0 + row + j - 127;
        qq[row][j] = (col >= 0 && col < NS) ? pL[row][col] : (ushort)0;
    }
    __syncthreads();

    // ---- phase G: ctx = P·V + pbar·table (two acc chains) ----
    const int d = wave*16 + lrow;
    const ushort* vTh = vT + ((size_t)bh*ND + d)*NS;
    const ushort* tTd = tabT + (size_t)d*256;
    f32x4 o0 = (f32x4){0.f,0.f,0.f,0.f};
    f32x4 o1 = (f32x4){0.f,0.f,0.f,0.f};
    #pragma unroll
    for (int k0 = 0; k0 < NS; k0 += 64){
        bf16x8 bv0 = *reinterpret_cast<const bf16x8*>(&vTh[k0 + lk8]);
        bf16x8 pa0 = *reinterpret_cast<const bf16x8*>(&pL[lrow][k0 + lk8]);
        o0 = __builtin_amdgcn_mfma_f32_16x16x32_bf16(pa0, bv0, o0, 0, 0, 0);
        bf16x8 bv1 = *reinterpret_cast<const bf16x8*>(&vTh[k0 + 32 + lk8]);
        bf16x8 pa1 = *reinterpret_cast<const bf16x8*>(&pL[lrow][k0 + 32 + lk8]);
        o1 = __builtin_amdgcn_mfma_f32_16x16x32_bf16(pa1, bv1, o1, 0, 0, 0);
    }
    #pragma unroll
    for (int k0 = 0; k0 < 256; k0 += 64){
        bf16x8 bv0 = *reinterpret_cast<const bf16x8*>(&tTd[k0 + lk8]);
        bf16x8 pa0 = *reinterpret_cast<const bf16x8*>(&qq[lrow][k0 + lk8]);
        o0 = __builtin_amdgcn_mfma_f32_16x16x32_bf16(pa0, bv0, o0, 0, 0, 0);
        bf16x8 bv1 = *reinterpret_cast<const bf16x8*>(&tTd[k0 + 32 + lk8]);
        bf16x8 pa1 = *reinterpret_cast<const bf16x8*>(&qq[lrow][k0 + 32 + lk8]);
        o1 = __builtin_amdgcn_mfma_f32_16x16x32_bf16(pa1, bv1, o1, 0, 0, 0);
    }
    #pragma unroll
    for (int r = 0; r < 4; ++r){
        int qo = q0 + g*4 + r;
        ctx[((size_t)b*NS + qo)*HID + h*ND + d] = o0[r] + o1[r];
    }
}

extern "C" void kernel_launch(void* const* d_in, const int* in_sizes, int n_in,
                              void* d_out, int out_size, void* d_ws, size_t ws_size,
                              hipStream_t stream)
{
    const float* x    = (const float*)d_in[0];
    const float* mask = (const float*)d_in[1];
    const float* Wq   = (const float*)d_in[2];
    const float* bq   = (const float*)d_in[3];
    const float* Wk   = (const float*)d_in[4];
    const float* bk   = (const float*)d_in[5];
    const float* Wv   = (const float*)d_in[6];
    const float* bv   = (const float*)d_in[7];

    float* out = (float*)d_out;
    float* ctx    = out;                      // [8][512][1024]
    float* scores = out + (size_t)NB*NS*HID;  // [8][16][512][512]

    char* ws = (char*)d_ws;
    ushort* x_bf  = (ushort*)ws;  ws += (size_t)NROWS*HID*2;
    ushort* wq_bf = (ushort*)ws;  ws += (size_t)HID*HID*2;
    ushort* wk_bf = (ushort*)ws;  ws += (size_t)HID*HID*2;
    ushort* wv_bf = (ushort*)ws;  ws += (size_t)HID*HID*2;
    ushort* q_bf  = (ushort*)ws;  ws += (size_t)NBH*NS*ND*2;
    ushort* k_bf  = (ushort*)ws;  ws += (size_t)NBH*NS*ND*2;
    ushort* vT_bf = (ushort*)ws;  ws += (size_t)NBH*NS*ND*2;
    ushort* tab   = (ushort*)ws;  ws += 256*64*2;
    ushort* tabT  = (ushort*)ws;  ws += 64*256*2;

    build_tables<<<64, 256, 0, stream>>>(tab, tabT);

    cvt_bf16<<<(NROWS*HID/4 + 255)/256, 256, 0, stream>>>(x, x_bf, NROWS*HID/4);
    cvt_bf16_w3<<<dim3((HID*HID/4 + 255)/256, 3), 256, 0, stream>>>(
        Wq, Wk, Wv, wq_bf, wk_bf, wv_bf, HID*HID/4);

    proj_gemm_qkv<<<dim3(24, 32), 256, 0, stream>>>(
        x_bf, wq_bf, wk_bf, wv_bf, bq, bk, bv, q_bf, k_bf, vT_bf);

    fused_attn<<<dim3(NBH, NS/16), 256, 0, stream>>>(
        q_bf, k_bf, vT_bf, tab, tabT, mask, scores, ctx);
}

// Round 7
// 180.218 us; speedup vs baseline: 2.1090x; 1.0122x over previous
//
#include <hip/hip_runtime.h>
#include <hip/hip_bf16.h>

typedef __attribute__((ext_vector_type(4))) float f32x4;
typedef __attribute__((ext_vector_type(8))) short bf16x8;

#define NB 8
#define NS 512
#define NH 16
#define ND 64
#define HID 1024
#define NBH (NB*NH)   // 128
#define NROWS (NB*NS) // 4096

static __device__ __forceinline__ ushort f2bf(float x){
    union{float f; unsigned u;} a; a.f = x;
    unsigned r = a.u + 0x7fffu + ((a.u >> 16) & 1u);
    return (ushort)(r >> 16);
}
static __device__ __forceinline__ float bf2f(ushort x){
    union{unsigned u; float f;} a; a.u = ((unsigned)x) << 16;
    return a.f;
}

// ---------------- kernel 1: sinusoidal rel table (255x64, padded to 256) ---
// row 255 and tabT col 255 are EXACT ZERO (relied on by fused_attn's aliased
// pbar buffer: stale bin 255 multiplies tabT col 255 == 0).
__global__ void build_tables(ushort* __restrict__ tab, ushort* __restrict__ tabT){
    int t = blockIdx.x * blockDim.x + threadIdx.x;
    if (t >= 256 * 64) return;
    int p = t >> 6, d = t & 63;
    float val = 0.f;
    if (p < 255){
        int i = d >> 1;
        float angle = (float)p / powf(10000.f, (float)i / 32.f);
        val = (d & 1) ? cosf(angle) : sinf(angle);
    }
    ushort b = f2bf(val);
    tab[p * 64 + d]  = b;
    tabT[d * 256 + p] = b;
}

// ---------------- kernel 2a: fp32 -> bf16 convert (hidden states) ----------
__global__ void cvt_bf16(const float* __restrict__ src, ushort* __restrict__ dst, int n4){
    int i = blockIdx.x * blockDim.x + threadIdx.x;
    if (i >= n4) return;
    float4 v = reinterpret_cast<const float4*>(src)[i];
    ushort4 o;
    o.x = f2bf(v.x); o.y = f2bf(v.y); o.z = f2bf(v.z); o.w = f2bf(v.w);
    reinterpret_cast<ushort4*>(dst)[i] = o;
}

// ---------------- kernel 2b: fp32 -> bf16 convert, 3 weights in one launch -
__global__ void cvt_bf16_w3(const float* __restrict__ w0, const float* __restrict__ w1,
                            const float* __restrict__ w2, ushort* __restrict__ o0,
                            ushort* __restrict__ o1, ushort* __restrict__ o2, int n4){
    int i = blockIdx.x * blockDim.x + threadIdx.x;
    if (i >= n4) return;
    const float* src = blockIdx.y == 0 ? w0 : (blockIdx.y == 1 ? w1 : w2);
    ushort* dst      = blockIdx.y == 0 ? o0 : (blockIdx.y == 1 ? o1 : o2);
    float4 v = reinterpret_cast<const float4*>(src)[i];
    ushort4 o;
    o.x = f2bf(v.x); o.y = f2bf(v.y); o.z = f2bf(v.z); o.w = f2bf(v.w);
    reinterpret_cast<ushort4*>(dst)[i] = o;
}

// ---------------- kernel 3: merged QKV projection GEMM --------------------
__global__ __launch_bounds__(256) void proj_gemm_qkv(
    const ushort* __restrict__ X,
    const ushort* __restrict__ Wqp, const ushort* __restrict__ Wkp, const ushort* __restrict__ Wvp,
    const float* __restrict__ bqp, const float* __restrict__ bkp, const float* __restrict__ bvp,
    ushort* __restrict__ outQ, ushort* __restrict__ outK, ushort* __restrict__ outV)
{
    __shared__ ushort lA[128][72];
    __shared__ ushort lB[128][72];
    int sel = blockIdx.x >> 3;
    const ushort* W   = sel == 0 ? Wqp : (sel == 1 ? Wkp : Wvp);
    const float* bias = sel == 0 ? bqp : (sel == 1 ? bkp : bvp);
    ushort* out       = sel == 0 ? outQ : (sel == 1 ? outK : outV);
    int n0 = (blockIdx.x & 7) * 128;
    int m0 = blockIdx.y * 128;
    int tid = threadIdx.x;
    int wave = tid >> 6, lane = tid & 63;
    int wr = (wave >> 1) * 64, wc = (wave & 1) * 64;
    int lrow = lane & 15, lk8 = (lane >> 4) * 8;

    f32x4 acc[4][4] = {};

    for (int k0 = 0; k0 < HID; k0 += 64){
        __syncthreads();
        #pragma unroll
        for (int i = 0; i < 4; ++i){
            int chunk = i * 256 + tid;
            int row = chunk >> 3, col = (chunk & 7) * 8;
            *reinterpret_cast<uint4*>(&lA[row][col]) =
                *reinterpret_cast<const uint4*>(&X[(size_t)(m0 + row) * HID + k0 + col]);
            *reinterpret_cast<uint4*>(&lB[row][col]) =
                *reinterpret_cast<const uint4*>(&W[(size_t)(n0 + row) * HID + k0 + col]);
        }
        __syncthreads();
        #pragma unroll
        for (int ks = 0; ks < 2; ++ks){
            bf16x8 af[4], bfr[4];
            #pragma unroll
            for (int m = 0; m < 4; ++m)
                af[m] = *reinterpret_cast<const bf16x8*>(&lA[wr + m*16 + lrow][ks*32 + lk8]);
            #pragma unroll
            for (int n = 0; n < 4; ++n)
                bfr[n] = *reinterpret_cast<const bf16x8*>(&lB[wc + n*16 + lrow][ks*32 + lk8]);
            #pragma unroll
            for (int m = 0; m < 4; ++m)
                #pragma unroll
                for (int n = 0; n < 4; ++n)
                    acc[m][n] = __builtin_amdgcn_mfma_f32_16x16x32_bf16(af[m], bfr[n], acc[m][n], 0, 0, 0);
        }
    }

    #pragma unroll
    for (int m = 0; m < 4; ++m){
        #pragma unroll
        for (int n = 0; n < 4; ++n){
            int col = n0 + wc + n*16 + lrow;
            float bv = bias[col];
            int h = col >> 6, d = col & 63;
            #pragma unroll
            for (int r = 0; r < 4; ++r){
                int mg = m0 + wr + m*16 + (lane >> 4)*4 + r;
                int b = mg >> 9, s = mg & 511;
                float val = acc[m][n][r] + bv;
                if (sel != 2)
                    out[(((size_t)(b*NH + h))*NS + s)*ND + d] = f2bf(val);
                else
                    out[(((size_t)(b*NH + h))*ND + d)*NS + s] = f2bf(val);
            }
        }
    }
}

// ---------------- kernel 4: fused scores+softmax+PV+P.rel -----------------
// Swapped QK^T (lane owns one q row, 4 consecutive k per reg). No max
// subtraction (|scores| <~ 12, exp safe in f32, softmax shift-invariant).
// LDS: row stride == 0 mod 128B + XOR chunk swizzle col^=(row&7)<<3
// (8-ushort chunks) -> conflict-free MFMA-operand reads (guide G4/T2).
// qq[] is qrel in B/C, pbar in E/F/G. Stale logical bin 255 (old qrel)
// multiplies tabT col 255 == 0. scores/ctx stored NONTEMPORAL so the
// 150 MB write stream does not evict K/V from L2.
__global__ __launch_bounds__(256) void fused_attn(
    const ushort* __restrict__ Qb, const ushort* __restrict__ Kb,
    const ushort* __restrict__ vT, const ushort* __restrict__ tab,
    const ushort* __restrict__ tabT, const float* __restrict__ mask,
    float* __restrict__ scores, float* __restrict__ ctx)
{
    __shared__ ushort pL[16][512];     // normalized probs (bf16), swizzled
    __shared__ ushort qq[16][256];     // qrel (B/C) then pbar (E/F/G), swizzled
    __shared__ float  rsum[16][4];
    __shared__ float  rleft[16][4];
    __shared__ float  rright[16][4];
    ushort* pLf = &pL[0][0];
    ushort* qqf = &qq[0][0];
#define SWZ(row, col) ((col) ^ (((row)&7)<<3))

    const int bh = blockIdx.x;         // bh fastest -> all q-blocks of one bh
    const int b = bh >> 4, h = bh & 15;//   land on the same XCD (bh % 8)
    const int q0 = blockIdx.y * 16;
    const int wave = threadIdx.x >> 6, lane = threadIdx.x & 63;
    const int lrow = lane & 15, g = lane >> 4, lk8 = g * 8;

    const ushort* Qh = Qb + (size_t)bh * NS * ND;
    const ushort* Kh = Kb + (size_t)bh * NS * ND;
    const int d = wave*16 + lrow;
    const ushort* vTh = vT + ((size_t)bh*ND + d)*NS;

    // ---- phase A: extended QK^T, swapped operands ----
    bf16x8 qf[2];
    #pragma unroll
    for (int ks = 0; ks < 2; ++ks)
        qf[ks] = *reinterpret_cast<const bf16x8*>(&Qh[(size_t)(q0 + lrow)*ND + ks*32 + lk8]);

    f32x4 acc[12];
    #pragma unroll
    for (int n = 0; n < 12; ++n) acc[n] = (f32x4){0.f, 0.f, 0.f, 0.f};

    #pragma unroll
    for (int n = 0; n < 12; ++n){
        const ushort* src = (n < 8) ? &Kh[(size_t)(wave*128 + n*16 + lrow)*ND]
                                    : &tab[(size_t)(wave*64 + (n-8)*16 + lrow)*ND];
        #pragma unroll
        for (int ks = 0; ks < 2; ++ks){
            bf16x8 kf = *reinterpret_cast<const bf16x8*>(&src[ks*32 + lk8]);
            acc[n] = __builtin_amdgcn_mfma_f32_16x16x32_bf16(kf, qf[ks], acc[n], 0, 0, 0);
        }
    }

    // ---- vT prefetch for the o0 MFMA chain (hides L2 latency under softmax)
    bf16x8 vpre[8];
    #pragma unroll
    for (int i = 0; i < 8; ++i)
        vpre[i] = *reinterpret_cast<const bf16x8*>(&vTh[i*64 + lk8]);

    // ---- phase B: stash qrel: lane owns q=lrow, bins consecutive in r ----
    #pragma unroll
    for (int n = 8; n < 12; ++n){
        ushort4 w;
        w.x = f2bf(acc[n][0]); w.y = f2bf(acc[n][1]);
        w.z = f2bf(acc[n][2]); w.w = f2bf(acc[n][3]);
        int col = wave*64 + (n-8)*16 + g*4;
        *reinterpret_cast<ushort4*>(&qqf[lrow*256 + SWZ(lrow, col)]) = w;
    }
    __syncthreads();

    // ---- phase C: scores + mask -> HBM (NT float4) ; exp ; partial sums ----
    const int q = q0 + lrow;
    float st = 0.f, sl = 0.f, sr = 0.f;
    #pragma unroll
    for (int n = 0; n < 8; ++n){
        int kbase = wave*128 + n*16 + g*4;
        float4 mk4 = *reinterpret_cast<const float4*>(&mask[b*NS + kbase]);
        float mk[4] = {mk4.x, mk4.y, mk4.z, mk4.w};
        f32x4 sv;
        #pragma unroll
        for (int r = 0; r < 4; ++r){
            int k = kbase + r;
            int dd = min(127, max(-127, k - q));
            float val = (acc[n][r] + bf2f(qqf[lrow*256 + SWZ(lrow, dd + 127)])) * 0.125f + mk[r];
            sv[r] = val;
            float e = __expf(val);
            acc[n][r] = e;
            st += e;
            if (k <= q - 127) sl += e;
            if (k >= q + 127) sr += e;
        }
        __builtin_nontemporal_store(sv,
            reinterpret_cast<f32x4*>(&scores[((size_t)bh*NS + q)*NS + kbase]));
    }
    // combine the 4 g-groups (same q, different k slices)
    st += __shfl_xor(st, 16); st += __shfl_xor(st, 32);
    sl += __shfl_xor(sl, 16); sl += __shfl_xor(sl, 32);
    sr += __shfl_xor(sr, 16); sr += __shfl_xor(sr, 32);
    if (lane < 16){
        rsum[lrow][wave] = st;
        rleft[lrow][wave] = sl;
        rright[lrow][wave] = sr;
    }
    __syncthreads();   // also ends qq-as-qrel liveness

    float T  = rsum[lrow][0] + rsum[lrow][1] + rsum[lrow][2] + rsum[lrow][3];
    float iv = 1.f / T;
    float Lv = (rleft[lrow][0] + rleft[lrow][1] + rleft[lrow][2] + rleft[lrow][3]) * iv;
    float Rv = (rright[lrow][0] + rright[lrow][1] + rright[lrow][2] + rright[lrow][3]) * iv;

    // ---- phase E: normalized probs -> pL (ushort4); edge bins -> qq ----
    #pragma unroll
    for (int n = 0; n < 8; ++n){
        int kbase = wave*128 + n*16 + g*4;
        ushort4 w;
        w.x = f2bf(acc[n][0] * iv); w.y = f2bf(acc[n][1] * iv);
        w.z = f2bf(acc[n][2] * iv); w.w = f2bf(acc[n][3] * iv);
        *reinterpret_cast<ushort4*>(&pLf[lrow*512 + SWZ(lrow, kbase)]) = w;
    }
    if (wave == 0 && lane < 16){
        qqf[lrow*256 + SWZ(lrow, 0)]   = f2bf(Lv);
        qqf[lrow*256 + SWZ(lrow, 254)] = f2bf(Rv);
    }
    __syncthreads();

    // ---- phase F: middle pbar bins = shifted copy of p row ----
    for (int idx = threadIdx.x; idx < 16*256; idx += 256){
        int row = idx >> 8, j = idx & 255;
        if (j == 0 || j >= 254) continue;
        int col = q0 + row + j - 127;
        qqf[row*256 + SWZ(row, j)] =
            (col >= 0 && col < NS) ? pLf[row*512 + SWZ(row, col)] : (ushort)0;
    }
    __syncthreads();

    // ---- phase G: ctx = P·V + pbar·table (two acc chains) ----
    const ushort* tTd = tabT + (size_t)d*256;
    f32x4 o0 = (f32x4){0.f,0.f,0.f,0.f};
    f32x4 o1 = (f32x4){0.f,0.f,0.f,0.f};
    #pragma unroll
    for (int i = 0; i < 8; ++i){
        int k0 = i*64;
        bf16x8 pa0 = *reinterpret_cast<const bf16x8*>(&pLf[lrow*512 + SWZ(lrow, k0 + lk8)]);
        o0 = __builtin_amdgcn_mfma_f32_16x16x32_bf16(pa0, vpre[i], o0, 0, 0, 0);
        bf16x8 bv1 = *reinterpret_cast<const bf16x8*>(&vTh[k0 + 32 + lk8]);
        bf16x8 pa1 = *reinterpret_cast<const bf16x8*>(&pLf[lrow*512 + SWZ(lrow, k0 + 32 + lk8)]);
        o1 = __builtin_amdgcn_mfma_f32_16x16x32_bf16(pa1, bv1, o1, 0, 0, 0);
    }
    #pragma unroll
    for (int k0 = 0; k0 < 256; k0 += 64){
        bf16x8 bv0 = *reinterpret_cast<const bf16x8*>(&tTd[k0 + lk8]);
        bf16x8 pa0 = *reinterpret_cast<const bf16x8*>(&qqf[lrow*256 + SWZ(lrow, k0 + lk8)]);
        o0 = __builtin_amdgcn_mfma_f32_16x16x32_bf16(pa0, bv0, o0, 0, 0, 0);
        bf16x8 bv1 = *reinterpret_cast<const bf16x8*>(&tTd[k0 + 32 + lk8]);
        bf16x8 pa1 = *reinterpret_cast<const bf16x8*>(&qqf[lrow*256 + SWZ(lrow, k0 + 32 + lk8)]);
        o1 = __builtin_amdgcn_mfma_f32_16x16x32_bf16(pa1, bv1, o1, 0, 0, 0);
    }
    #pragma unroll
    for (int r = 0; r < 4; ++r){
        int qo = q0 + g*4 + r;
        __builtin_nontemporal_store(o0[r] + o1[r],
            &ctx[((size_t)b*NS + qo)*HID + h*ND + d]);
    }
#undef SWZ
}

extern "C" void kernel_launch(void* const* d_in, const int* in_sizes, int n_in,
                              void* d_out, int out_size, void* d_ws, size_t ws_size,
                              hipStream_t stream)
{
    const float* x    = (const float*)d_in[0];
    const float* mask = (const float*)d_in[1];
    const float* Wq   = (const float*)d_in[2];
    const float* bq   = (const float*)d_in[3];
    const float* Wk   = (const float*)d_in[4];
    const float* bk   = (const float*)d_in[5];
    const float* Wv   = (const float*)d_in[6];
    const float* bv   = (const float*)d_in[7];

    float* out = (float*)d_out;
    float* ctx    = out;                      // [8][512][1024]
    float* scores = out + (size_t)NB*NS*HID;  // [8][16][512][512]

    char* ws = (char*)d_ws;
    ushort* x_bf  = (ushort*)ws;  ws += (size_t)NROWS*HID*2;
    ushort* wq_bf = (ushort*)ws;  ws += (size_t)HID*HID*2;
    ushort* wk_bf = (ushort*)ws;  ws += (size_t)HID*HID*2;
    ushort* wv_bf = (ushort*)ws;  ws += (size_t)HID*HID*2;
    ushort* q_bf  = (ushort*)ws;  ws += (size_t)NBH*NS*ND*2;
    ushort* k_bf  = (ushort*)ws;  ws += (size_t)NBH*NS*ND*2;
    ushort* vT_bf = (ushort*)ws;  ws += (size_t)NBH*NS*ND*2;
    ushort* tab   = (ushort*)ws;  ws += 256*64*2;
    ushort* tabT  = (ushort*)ws;  ws += 64*256*2;

    build_tables<<<64, 256, 0, stream>>>(tab, tabT);

    cvt_bf16<<<(NROWS*HID/4 + 255)/256, 256, 0, stream>>>(x, x_bf, NROWS*HID/4);
    cvt_bf16_w3<<<dim3((HID*HID/4 + 255)/256, 3), 256, 0, stream>>>(
        Wq, Wk, Wv, wq_bf, wk_bf, wv_bf, HID*HID/4);

    proj_gemm_qkv<<<dim3(24, 32), 256, 0, stream>>>(
        x_bf, wq_bf, wk_bf, wv_bf, bq, bk, bv, q_bf, k_bf, vT_bf);

    fused_attn<<<dim3(NBH, NS/16), 256, 0, stream>>>(
        q_bf, k_bf, vT_bf, tab, tabT, mask, scores, ctx);
}